// Round 2
// 203.753 us; speedup vs baseline: 1.0058x; 1.0058x over previous
//
#include <hip/hip_runtime.h>
#include <math.h>

// Problem constants
#define BATCH 2
#define SEQ   2048
#define NH    16
#define HD    64
#define DM    1024
#define MROWS (BATCH * SEQ)                  // 4096
#define NEL   ((size_t)MROWS * DM)           // 4 M elements (activation buffer)
#define WEL   ((size_t)DM * DM)              // 1 M elements (weight buffer)
// softmax scale folded into Q at projection: 1/sqrt(64) * log2(e)
#define SM_SCALE_LOG2E 0.18033688011112042f

typedef __bf16 bf16x8 __attribute__((ext_vector_type(8)));
typedef float  f32x4  __attribute__((ext_vector_type(4)));

#define MFMA16(a, b, c) __builtin_amdgcn_mfma_f32_16x16x32_bf16((a), (b), (c), 0, 0, 0)
#define EXP2(x) __builtin_amdgcn_exp2f(x)

// async global->LDS, 16B per lane; LDS dest = wave-uniform base + lane*16
#define GLDS16(g, s) __builtin_amdgcn_global_load_lds( \
    (const __attribute__((address_space(1))) void*)(g), \
    (__attribute__((address_space(3))) void*)(s), 16, 0, 0)

// ----------------------------------------------------------------------
// LDS bank-conflict swizzle (T2, rule #21: both-sides-or-neither).
// All MFMA fragment reads use ds_read_b128 at [row*64B + chunk*16B] with
// 16 distinct rows per quad-phase -> half-wave phases touch only 16 of 32
// banks (2x conflict, +8 cyc/read; matches measured 7.37M conflict cycles).
// Fix: chunk' = chunk ^ ((row>>1)&3). Staging pre-swizzles the GLOBAL
// source column (LDS dest stays linear, as global_load_lds requires);
// reads apply the same XOR keyed on row bits 1..2 (== l15 bits 1..2).
// ----------------------------------------------------------------------

// ======================================================================
// fp32 -> bf16 converts
// ======================================================================
__global__ __launch_bounds__(256) void cvt_x(const float* __restrict__ src,
                                             __bf16* __restrict__ dst) {
    const size_t i = ((size_t)blockIdx.x * 256 + threadIdx.x) * 4;
    const float4 f = *(const float4*)&src[i];
    __bf16 b[4] = {(__bf16)f.x, (__bf16)f.y, (__bf16)f.z, (__bf16)f.w};
    *(ushort4*)&dst[i] = *(ushort4*)b;
}

__global__ __launch_bounds__(256) void cvt_w(const float* __restrict__ w0,
                                             const float* __restrict__ w1,
                                             const float* __restrict__ w2,
                                             const float* __restrict__ w3,
                                             __bf16* __restrict__ dst) {
    const int z = blockIdx.z;
    const float* src = (z == 0) ? w0 : (z == 1) ? w1 : (z == 2) ? w2 : w3;
    __bf16* d = dst + (size_t)z * WEL;
    const size_t i = ((size_t)blockIdx.x * 256 + threadIdx.x) * 4;
    const float4 f = *(const float4*)&src[i];
    __bf16 b[4] = {(__bf16)f.x, (__bf16)f.y, (__bf16)f.z, (__bf16)f.w};
    *(ushort4*)&d[i] = *(ushort4*)b;
}

// ======================================================================
// NT bf16 MFMA GEMM, single-barrier double-buffered K-loop.
// C[m,n] = sum_k A[m,k]*W[n,k]. Tile 128 x BN, BK=32, 4 waves.
// Per iter: prefetch tile i+1 into buf^1 (GLDS), compute tile i from
// buf, ONE __syncthreads (its vmcnt(0) drain sits a full compute phase
// after the loads were issued -> real overlap, unlike the 2-barrier
// m97 loop whose drain is issue-to-use).
// LDS k-chunk XOR-swizzled (see header comment) -> conflict-free b128.
// mode 1 (BN=128): z selects weight+output slab; bf16 store permuted to
//   (B,H,S,HD); z==0 (Q) pre-scaled; z==2 (V) dual-stored to Vt.
// mode 0: fp32 row-major M x DM store.
// ======================================================================
template<int BN>
__global__ __launch_bounds__(256) void gemm_nt_mfma(
    const __bf16* __restrict__ A, const __bf16* __restrict__ W0,
    void* __restrict__ C0, __bf16* __restrict__ Vt, int mode)
{
    constexpr int NI  = BN / 32;         // 16-col groups per wave
    constexpr int NIT = DM / 32;         // 32 K-iterations
    __shared__ __bf16 Ast[2][128 * 32];
    __shared__ __bf16 Bst[2][BN * 32];

    const int t = threadIdx.x;
    const int w = t >> 6, l = t & 63;
    const int quad = l >> 4, l15 = l & 15;
    const int z = blockIdx.z;
    const int m0 = blockIdx.y * 128, n0 = blockIdx.x * BN;
    const int wm = (w >> 1) * 64, wn = (w & 1) * (BN / 2);

    const __bf16* Wp = W0 + (size_t)z * WEL;

    const int lrow = l >> 2;           // staging: lane row within 16-row instr
    // staging k-offset: pre-swizzled global source column (rule #21)
    const int lkof = ((l & 3) ^ ((lrow >> 1) & 3)) * 8;
    // read-side swizzled k-chunk (row bits 1..2 == l15 bits 1..2)
    const int qsw = (quad ^ ((l15 >> 1) & 3)) * 8;

    const __bf16* Ag = A + (size_t)(m0 + w * 32 + lrow) * DM + lkof;
    const int aoff = (w * 32) * 32;    // wave-uniform LDS offset (A)
    // B staging: BN=128 -> 2 instrs/wave (rows w*32); BN=64 -> 1 (rows w*16)
    const int brow = (BN == 128) ? (w * 32) : (w * 16);
    const __bf16* Bg = Wp + (size_t)(n0 + brow + lrow) * DM + lkof;
    const int boff = brow * 32;

    f32x4 acc[4][NI];
    #pragma unroll
    for (int i = 0; i < 4; i++)
        #pragma unroll
        for (int j = 0; j < NI; j++) acc[i][j] = (f32x4)0.0f;

    // prologue: tile 0 -> buf 0
    GLDS16(Ag,           &Ast[0][aoff]);
    GLDS16(Ag + 16 * DM, &Ast[0][aoff + 512]);
    GLDS16(Bg,           &Bst[0][boff]);
    if (BN == 128) GLDS16(Bg + 16 * DM, &Bst[0][boff + 512]);
    __syncthreads();

    for (int i = 0; i < NIT; i++) {
        const int cur = i & 1, nxt = cur ^ 1;
        if (i + 1 < NIT) {
            const int k0 = (i + 1) * 32;
            GLDS16(Ag + k0,           &Ast[nxt][aoff]);
            GLDS16(Ag + k0 + 16 * DM, &Ast[nxt][aoff + 512]);
            GLDS16(Bg + k0,           &Bst[nxt][boff]);
            if (BN == 128) GLDS16(Bg + k0 + 16 * DM, &Bst[nxt][boff + 512]);
        }

        bf16x8 af[4], bfr[NI];
        #pragma unroll
        for (int mi = 0; mi < 4; mi++)
            af[mi] = *(const bf16x8*)&Ast[cur][(wm + mi * 16 + l15) * 32 + qsw];
        #pragma unroll
        for (int ni = 0; ni < NI; ni++)
            bfr[ni] = *(const bf16x8*)&Bst[cur][(wn + ni * 16 + l15) * 32 + qsw];
        #pragma unroll
        for (int mi = 0; mi < 4; mi++)
            #pragma unroll
            for (int ni = 0; ni < NI; ni++)
                acc[mi][ni] = MFMA16(af[mi], bfr[ni], acc[mi][ni]);

        __syncthreads();   // single barrier: drains prefetch, fences buffers
    }

    if (mode) {
        const float sc = (z == 0) ? SM_SCALE_LOG2E : 1.0f;
        __bf16* C = (__bf16*)C0 + (size_t)z * NEL;
        #pragma unroll
        for (int mi = 0; mi < 4; mi++)
            #pragma unroll
            for (int ni = 0; ni < NI; ni++)
                #pragma unroll
                for (int r = 0; r < 4; r++) {
                    const int row = m0 + wm + mi * 16 + quad * 4 + r;
                    const int col = n0 + wn + ni * 16 + l15;
                    const int b = row >> 11, s = row & (SEQ - 1);
                    const int h = col >> 6,  d = col & (HD - 1);
                    const __bf16 val = (__bf16)(acc[mi][ni][r] * sc);
                    C[((size_t)(b * NH + h) * SEQ + s) * HD + d] = val;
                    if (z == 2)   // V: also store transposed (B,H,HD,S)
                        Vt[((size_t)(b * NH + h) * HD + d) * SEQ + s] = val;
                }
    } else {
        float* C = (float*)C0;
        #pragma unroll
        for (int mi = 0; mi < 4; mi++)
            #pragma unroll
            for (int ni = 0; ni < NI; ni++)
                #pragma unroll
                for (int r = 0; r < 4; r++) {
                    const int row = m0 + wm + mi * 16 + quad * 4 + r;
                    const int col = n0 + wn + ni * 16 + l15;
                    C[(size_t)row * DM + col] = acc[mi][ni][r];
                }
    }
}

// ======================================================================
// Flash attention v5: v4 + LDS k-chunk XOR-swizzle on K/V/Q tiles.
// Transposed-score MFMA formulation, fixed-shift softmax, fused
// subtract-projection, Q fragments hoisted to registers, single-barrier
// double-buffered K/V staging.
// Block = 128 queries of one (b,h), 4 waves, 32 q/wave.
// LDS: KV dbuf 32 KB + Pt 18 KB = 50 KB -> 3 blocks/CU (grid caps at 2).
// Pt keeps the +72 pad (already conflict-free; not swizzled).
// ======================================================================
__global__ __launch_bounds__(256, 3) void attn_mfma(
    const __bf16* __restrict__ Q, const __bf16* __restrict__ K,
    const __bf16* __restrict__ Vt, const __bf16* __restrict__ V,
    const float* __restrict__ xsa, __bf16* __restrict__ X2)
{
    // KV[buf][0] = K region [half][key][32]; KV[buf][1] = V region
    // [keyhalf][dim][32]. Each region 4096 elems (8 KB).
    __shared__ __bf16 KV[2][2][2 * 64 * 32];
    __shared__ __bf16 Pt[4][32][72];   // per-wave P [q][key+pad]  18 KB

    const int t = threadIdx.x;
    const int w = t >> 6, l = t & 63;
    const int quad = l >> 4, l15 = l & 15;
    const int bh = blockIdx.y;
    const int q0 = blockIdx.x * 128;

    const __bf16* Qb  = Q  + (size_t)bh * SEQ * HD;
    const __bf16* Kb  = K  + (size_t)bh * SEQ * HD;
    const __bf16* Vtb = Vt + (size_t)bh * HD * SEQ;

    const int lrow = l >> 2;
    // staging k-offset: pre-swizzled global source column (rule #21)
    const int lkof = ((l & 3) ^ ((lrow >> 1) & 3)) * 8;
    // read-side swizzled k-chunk
    const int qsw = (quad ^ ((l15 >> 1) & 3)) * 8;

    // ---- prologue: stage Q into KV[1] (16 KB overlay) + K0/V0 into KV[0]
    __bf16* Qst = &KV[1][0][0];   // flat [h][q][32]: h*4096 + q*32 + j
    #pragma unroll
    for (int h = 0; h < 2; h++)
        #pragma unroll
        for (int qq = 0; qq < 2; qq++)
            GLDS16(Qb + (size_t)(q0 + w * 32 + qq * 16 + lrow) * HD + h * 32 + lkof,
                   Qst + h * 4096 + (w * 32 + qq * 16) * 32);
    #pragma unroll
    for (int h = 0; h < 2; h++)
        GLDS16(Kb + (size_t)(w * 16 + lrow) * HD + h * 32 + lkof,
               &KV[0][0][h * 2048 + (w * 16) * 32]);
    #pragma unroll
    for (int kh = 0; kh < 2; kh++)
        GLDS16(Vtb + (size_t)(w * 16 + lrow) * SEQ + kh * 32 + lkof,
               &KV[0][1][kh * 2048 + (w * 16) * 32]);
    __syncthreads();   // all prologue staging visible

    // ---- hoist Q fragments to registers (loop-invariant) ----
    bf16x8 qf[2][2];   // [half][mi]
    #pragma unroll
    for (int h = 0; h < 2; h++)
        #pragma unroll
        for (int mi = 0; mi < 2; mi++)
            qf[h][mi] = *(const bf16x8*)&Qst[h * 4096 +
                          (w * 32 + mi * 16 + l15) * 32 + qsw];
    __syncthreads();   // Q reads done before kt=0 prefetch overwrites KV[1]

    float l_i[2] = {0.0f, 0.0f};
    f32x4 o[2][4];
    #pragma unroll
    for (int mi = 0; mi < 2; mi++)
        #pragma unroll
        for (int db = 0; db < 4; db++) o[mi][db] = (f32x4)0.0f;

    constexpr int NT = SEQ / 64;   // 32 key tiles
    for (int kt = 0; kt < NT; kt++) {
        const int cur = kt & 1, nxt = cur ^ 1;
        if (kt + 1 < NT) {
            const int k0n = (kt + 1) * 64;
            #pragma unroll
            for (int h = 0; h < 2; h++)
                GLDS16(Kb + (size_t)(k0n + w * 16 + lrow) * HD + h * 32 + lkof,
                       &KV[nxt][0][h * 2048 + (w * 16) * 32]);
            #pragma unroll
            for (int kh = 0; kh < 2; kh++)
                GLDS16(Vtb + (size_t)(w * 16 + lrow) * SEQ + k0n + kh * 32 + lkof,
                       &KV[nxt][1][kh * 2048 + (w * 16) * 32]);
        }
        const __bf16* Ks = &KV[cur][0][0];
        const __bf16* Vs = &KV[cur][1][0];

        // ---- S^T = K Q^T : 64k x 32q x 64d per wave (16 MFMAs) ----
        f32x4 st[2][4];
        #pragma unroll
        for (int mi = 0; mi < 2; mi++)
            #pragma unroll
            for (int kb = 0; kb < 4; kb++) st[mi][kb] = (f32x4)0.0f;
        #pragma unroll
        for (int h = 0; h < 2; h++)
            #pragma unroll
            for (int kb = 0; kb < 4; kb++) {
                const bf16x8 kf = *(const bf16x8*)&Ks[h * 2048 +
                                      (kb * 16 + l15) * 32 + qsw];
                #pragma unroll
                for (int mi = 0; mi < 2; mi++)
                    st[mi][kb] = MFMA16(kf, qf[h][mi], st[mi][kb]);
            }

        // ---- fixed-shift softmax: p = exp2(s), accumulate l ----
        #pragma unroll
        for (int mi = 0; mi < 2; mi++) {
            float rs = 0.0f;
            #pragma unroll
            for (int kb = 0; kb < 4; kb++)
                #pragma unroll
                for (int r = 0; r < 4; r++) {
                    const float p = EXP2(st[mi][kb][r]);
                    st[mi][kb][r] = p;
                    rs += p;
                }
            rs += __shfl_xor(rs, 16);
            rs += __shfl_xor(rs, 32);
            l_i[mi] += rs;
            #pragma unroll
            for (int kb = 0; kb < 4; kb++) {
                __bf16 pb[4] = {(__bf16)st[mi][kb][0], (__bf16)st[mi][kb][1],
                                (__bf16)st[mi][kb][2], (__bf16)st[mi][kb][3]};
                *(uint2*)&Pt[w][mi * 16 + l15][kb * 16 + quad * 4] = *(uint2*)pb;
            }
        }

        // ---- O^T += V^T P^T : 64d x 32q x 64k per wave (16 MFMAs) ----
        #pragma unroll
        for (int kh = 0; kh < 2; kh++) {
            bf16x8 pf[2];
            #pragma unroll
            for (int mi = 0; mi < 2; mi++)
                pf[mi] = *(const bf16x8*)&Pt[w][mi * 16 + l15][kh * 32 + quad * 8];
            #pragma unroll
            for (int db = 0; db < 4; db++) {
                const bf16x8 vf = *(const bf16x8*)&Vs[kh * 2048 +
                                      (db * 16 + l15) * 32 + qsw];
                #pragma unroll
                for (int mi = 0; mi < 2; mi++)
                    o[mi][db] = MFMA16(vf, pf[mi], o[mi][db]);
            }
        }

        __syncthreads();   // single barrier: drains prefetch, fences buffers
    }

    // ---- epilogue: normalize, fused subtract-projection, store X2 ----
    const float xs = xsa[0];
    const int b = bh >> 4, h = bh & (NH - 1);
    const __bf16* Vb = V + (size_t)bh * SEQ * HD;
    #pragma unroll
    for (int mi = 0; mi < 2; mi++) {
        const int q = q0 + w * 32 + mi * 16 + l15;   // sequence position
        const float inv = 1.0f / l_i[mi];
        float vv[4][4], on[4][4];
        float dp = 0.0f, nn = 0.0f;
        #pragma unroll
        for (int db = 0; db < 4; db++) {
            __bf16 vb4[4];
            *(uint2*)vb4 = *(const uint2*)&Vb[(size_t)q * HD + db * 16 + quad * 4];
            #pragma unroll
            for (int r = 0; r < 4; r++) {
                const float vf = (float)vb4[r];
                const float of = o[mi][db][r] * inv;
                vv[db][r] = vf;
                on[db][r] = of;
                dp += of * vf;
                nn += vf * vf;
            }
        }
        dp += __shfl_xor(dp, 16); dp += __shfl_xor(dp, 32);
        nn += __shfl_xor(nn, 16); nn += __shfl_xor(nn, 32);
        const float coef = xs * dp / (nn + 1e-8f);
        #pragma unroll
        for (int db = 0; db < 4; db++) {
            __bf16 ob[4];
            #pragma unroll
            for (int r = 0; r < 4; r++)
                ob[r] = (__bf16)(on[db][r] - coef * vv[db][r]);
            *(uint2*)&X2[((size_t)b * SEQ + q) * DM + h * HD + db * 16 + quad * 4] =
                *(uint2*)ob;
        }
    }
}

// ======================================================================
extern "C" void kernel_launch(void* const* d_in, const int* in_sizes, int n_in,
                              void* d_out, int out_size, void* d_ws, size_t ws_size,
                              hipStream_t stream)
{
    (void)in_sizes; (void)n_in; (void)out_size; (void)ws_size;
    const float* x   = (const float*)d_in[0];
    const float* Wq  = (const float*)d_in[1];
    const float* Wk  = (const float*)d_in[2];
    const float* Wv  = (const float*)d_in[3];
    const float* Wo  = (const float*)d_in[4];
    const float* xsa = (const float*)d_in[5];
    float* out = (float*)d_out;

    // workspace layout (bf16 elements): 56 MB total
    __bf16* xb  = (__bf16*)d_ws;        // 4 M
    __bf16* Wb  = xb  + NEL;            // 4 x 1 M (Wq,Wk,Wv,Wo)
    __bf16* Qb  = Wb  + 4 * WEL;        // 4 M  (B,H,S,HD), pre-scaled
    __bf16* Kb  = Qb  + NEL;            // 4 M
    __bf16* Vb  = Kb  + NEL;            // 4 M
    __bf16* Vtb = Vb  + NEL;            // 4 M  (B,H,HD,S)
    __bf16* X2  = Vtb + NEL;            // 4 M  (B,S,DM)

    cvt_x<<<dim3(NEL / 1024), 256, 0, stream>>>(x, xb);
    cvt_w<<<dim3(WEL / 1024, 1, 4), 256, 0, stream>>>(Wq, Wk, Wv, Wo, Wb);

    // Q/K/V projections (V dual-stored to Vt; Q pre-scaled)
    gemm_nt_mfma<128><<<dim3(DM / 128, MROWS / 128, 3), 256, 0, stream>>>(
        xb, Wb, Qb, Vtb, 1);

    // attention + fused subtract-projection -> X2
    attn_mfma<<<dim3(SEQ / 128, BATCH * NH), 256, 0, stream>>>(
        Qb, Kb, Vtb, Vb, xsa, X2);

    // output projection (BN=64 -> 512 blocks for occupancy), fp32 out
    gemm_nt_mfma<64><<<dim3(DM / 64, MROWS / 128, 1), 256, 0, stream>>>(
        X2, Wb + 3 * WEL, out, nullptr, 0);
}

// Round 3
// 198.719 us; speedup vs baseline: 1.0313x; 1.0253x over previous
//
#include <hip/hip_runtime.h>
#include <math.h>

// Problem constants
#define BATCH 2
#define SEQ   2048
#define NH    16
#define HD    64
#define DM    1024
#define MROWS (BATCH * SEQ)                  // 4096
#define NEL   ((size_t)MROWS * DM)           // 4 M elements (activation buffer)
#define WEL   ((size_t)DM * DM)              // 1 M elements (weight buffer)
// softmax scale folded into Q at projection: 1/sqrt(64) * log2(e)
#define SM_SCALE_LOG2E 0.18033688011112042f

typedef __bf16 bf16x8 __attribute__((ext_vector_type(8)));
typedef float  f32x4  __attribute__((ext_vector_type(4)));

#define MFMA16(a, b, c) __builtin_amdgcn_mfma_f32_16x16x32_bf16((a), (b), (c), 0, 0, 0)
#define EXP2(x) __builtin_amdgcn_exp2f(x)

// async global->LDS, 16B per lane; LDS dest = wave-uniform base + lane*16
#define GLDS16(g, s) __builtin_amdgcn_global_load_lds( \
    (const __attribute__((address_space(1))) void*)(g), \
    (__attribute__((address_space(3))) void*)(s), 16, 0, 0)

// ----------------------------------------------------------------------
// LDS bank-conflict swizzle (T2, rule #21: both-sides-or-neither).
// K/V/Q tiles [row][32]: chunk' = chunk ^ ((row>>1)&3), staged via
// pre-swizzled GLOBAL source column (LDS dest linear for global_load_lds),
// read with the same XOR. Verified R2: conflicts 7.37M -> 3.15M.
// Pt [row][64] (plain ds ops): 16B-chunk swizzle chunk' = chunk ^ (row&7)
// on both ds_write and ds_read -> removes the remaining ~2.1M conflicts
// (72-pad had bank stride 36 = 4 mod 32 -> rows l15/l15+8 aliased 2-way).
// ----------------------------------------------------------------------

// ======================================================================
// fp32 -> bf16 converts
// ======================================================================
__global__ __launch_bounds__(256) void cvt_x(const float* __restrict__ src,
                                             __bf16* __restrict__ dst) {
    const size_t i = ((size_t)blockIdx.x * 256 + threadIdx.x) * 4;
    const float4 f = *(const float4*)&src[i];
    __bf16 b[4] = {(__bf16)f.x, (__bf16)f.y, (__bf16)f.z, (__bf16)f.w};
    *(ushort4*)&dst[i] = *(ushort4*)b;
}

__global__ __launch_bounds__(256) void cvt_w(const float* __restrict__ w0,
                                             const float* __restrict__ w1,
                                             const float* __restrict__ w2,
                                             const float* __restrict__ w3,
                                             __bf16* __restrict__ dst) {
    const int z = blockIdx.z;
    const float* src = (z == 0) ? w0 : (z == 1) ? w1 : (z == 2) ? w2 : w3;
    __bf16* d = dst + (size_t)z * WEL;
    const size_t i = ((size_t)blockIdx.x * 256 + threadIdx.x) * 4;
    const float4 f = *(const float4*)&src[i];
    __bf16 b[4] = {(__bf16)f.x, (__bf16)f.y, (__bf16)f.z, (__bf16)f.w};
    *(ushort4*)&d[i] = *(ushort4*)b;
}

// ======================================================================
// NT bf16 MFMA GEMM, single-barrier double-buffered K-loop.
// C[m,n] = sum_k A[m,k]*W[n,k]. Tile 128 x BN, BK=32, 4 waves.
// LDS k-chunk XOR-swizzled -> conflict-free b128 fragment reads.
// mode 1 (BN=128): z selects weight+output slab; bf16 store permuted to
//   (B,H,S,HD); z==0 (Q) pre-scaled; z==2 (V) dual-stored to Vt.
// mode 0: fp32 row-major M x DM store.
// ======================================================================
template<int BN>
__global__ __launch_bounds__(256) void gemm_nt_mfma(
    const __bf16* __restrict__ A, const __bf16* __restrict__ W0,
    void* __restrict__ C0, __bf16* __restrict__ Vt, int mode)
{
    constexpr int NI  = BN / 32;         // 16-col groups per wave
    constexpr int NIT = DM / 32;         // 32 K-iterations
    __shared__ __bf16 Ast[2][128 * 32];
    __shared__ __bf16 Bst[2][BN * 32];

    const int t = threadIdx.x;
    const int w = t >> 6, l = t & 63;
    const int quad = l >> 4, l15 = l & 15;
    const int z = blockIdx.z;
    const int m0 = blockIdx.y * 128, n0 = blockIdx.x * BN;
    const int wm = (w >> 1) * 64, wn = (w & 1) * (BN / 2);

    const __bf16* Wp = W0 + (size_t)z * WEL;

    const int lrow = l >> 2;           // staging: lane row within 16-row instr
    // staging k-offset: pre-swizzled global source column (rule #21)
    const int lkof = ((l & 3) ^ ((lrow >> 1) & 3)) * 8;
    // read-side swizzled k-chunk (row bits 1..2 == l15 bits 1..2)
    const int qsw = (quad ^ ((l15 >> 1) & 3)) * 8;

    const __bf16* Ag = A + (size_t)(m0 + w * 32 + lrow) * DM + lkof;
    const int aoff = (w * 32) * 32;    // wave-uniform LDS offset (A)
    // B staging: BN=128 -> 2 instrs/wave (rows w*32); BN=64 -> 1 (rows w*16)
    const int brow = (BN == 128) ? (w * 32) : (w * 16);
    const __bf16* Bg = Wp + (size_t)(n0 + brow + lrow) * DM + lkof;
    const int boff = brow * 32;

    f32x4 acc[4][NI];
    #pragma unroll
    for (int i = 0; i < 4; i++)
        #pragma unroll
        for (int j = 0; j < NI; j++) acc[i][j] = (f32x4)0.0f;

    // prologue: tile 0 -> buf 0
    GLDS16(Ag,           &Ast[0][aoff]);
    GLDS16(Ag + 16 * DM, &Ast[0][aoff + 512]);
    GLDS16(Bg,           &Bst[0][boff]);
    if (BN == 128) GLDS16(Bg + 16 * DM, &Bst[0][boff + 512]);
    __syncthreads();

    for (int i = 0; i < NIT; i++) {
        const int cur = i & 1, nxt = cur ^ 1;
        if (i + 1 < NIT) {
            const int k0 = (i + 1) * 32;
            GLDS16(Ag + k0,           &Ast[nxt][aoff]);
            GLDS16(Ag + k0 + 16 * DM, &Ast[nxt][aoff + 512]);
            GLDS16(Bg + k0,           &Bst[nxt][boff]);
            if (BN == 128) GLDS16(Bg + k0 + 16 * DM, &Bst[nxt][boff + 512]);
        }

        bf16x8 af[4], bfr[NI];
        #pragma unroll
        for (int mi = 0; mi < 4; mi++)
            af[mi] = *(const bf16x8*)&Ast[cur][(wm + mi * 16 + l15) * 32 + qsw];
        #pragma unroll
        for (int ni = 0; ni < NI; ni++)
            bfr[ni] = *(const bf16x8*)&Bst[cur][(wn + ni * 16 + l15) * 32 + qsw];
        #pragma unroll
        for (int mi = 0; mi < 4; mi++)
            #pragma unroll
            for (int ni = 0; ni < NI; ni++)
                acc[mi][ni] = MFMA16(af[mi], bfr[ni], acc[mi][ni]);

        __syncthreads();   // single barrier: drains prefetch, fences buffers
    }

    if (mode) {
        const float sc = (z == 0) ? SM_SCALE_LOG2E : 1.0f;
        __bf16* C = (__bf16*)C0 + (size_t)z * NEL;
        #pragma unroll
        for (int mi = 0; mi < 4; mi++)
            #pragma unroll
            for (int ni = 0; ni < NI; ni++)
                #pragma unroll
                for (int r = 0; r < 4; r++) {
                    const int row = m0 + wm + mi * 16 + quad * 4 + r;
                    const int col = n0 + wn + ni * 16 + l15;
                    const int b = row >> 11, s = row & (SEQ - 1);
                    const int h = col >> 6,  d = col & (HD - 1);
                    const __bf16 val = (__bf16)(acc[mi][ni][r] * sc);
                    C[((size_t)(b * NH + h) * SEQ + s) * HD + d] = val;
                    if (z == 2)   // V: also store transposed (B,H,HD,S)
                        Vt[((size_t)(b * NH + h) * HD + d) * SEQ + s] = val;
                }
    } else {
        float* C = (float*)C0;
        #pragma unroll
        for (int mi = 0; mi < 4; mi++)
            #pragma unroll
            for (int ni = 0; ni < NI; ni++)
                #pragma unroll
                for (int r = 0; r < 4; r++) {
                    const int row = m0 + wm + mi * 16 + quad * 4 + r;
                    const int col = n0 + wn + ni * 16 + l15;
                    C[(size_t)row * DM + col] = acc[mi][ni][r];
                }
    }
}

// ======================================================================
// Flash attention v6: v5 + XCD-pinned 1D grid + fully-swizzled Pt.
//  - grid = 512 (1D); bh = id & 31, qtile = id >> 5. id%8 == bh%8, so all
//    16 q-tile blocks of one (b,h) land on the SAME XCD -> its K+Vt
//    (512 KB; 4 bh/XCD = 2 MB) is L2-resident after first touch. Fixes
//    the measured 2.3x L2-miss amplification (FETCH 73.8 MB vs 32 MB
//    unique) that made per-tile prefetches miss and stall the barrier.
//  - Pt: [32][64] unpadded, 16B-chunk XOR swizzle (chunk ^= row&7) on
//    write AND read -> conflict-free (old 72-pad aliased rows l15/l15+8
//    2-way: the remaining 3.15M conflict cycles).
// Block = 128 queries of one (b,h), 4 waves, 32 q/wave.
// LDS: KV dbuf 32 KB + Pt 16 KB = 48 KB.
// ======================================================================
__global__ __launch_bounds__(256, 3) void attn_mfma(
    const __bf16* __restrict__ Q, const __bf16* __restrict__ K,
    const __bf16* __restrict__ Vt, const __bf16* __restrict__ V,
    const float* __restrict__ xsa, __bf16* __restrict__ X2)
{
    // KV[buf][0] = K region [half][key][32]; KV[buf][1] = V region
    // [keyhalf][dim][32]. Each region 4096 elems (8 KB).
    __shared__ __bf16 KV[2][2][2 * 64 * 32];
    __shared__ __bf16 Pt[4][32][64];   // per-wave P [q][key], XOR-swizzled

    const int t = threadIdx.x;
    const int w = t >> 6, l = t & 63;
    const int quad = l >> 4, l15 = l & 15;
    // XCD-pinned decomposition: id%8 == bh%8 -> one XCD per (b,h)
    const int bh = blockIdx.x & 31;
    const int q0 = (blockIdx.x >> 5) * 128;

    const __bf16* Qb  = Q  + (size_t)bh * SEQ * HD;
    const __bf16* Kb  = K  + (size_t)bh * SEQ * HD;
    const __bf16* Vtb = Vt + (size_t)bh * HD * SEQ;

    const int lrow = l >> 2;
    // staging k-offset: pre-swizzled global source column (rule #21)
    const int lkof = ((l & 3) ^ ((lrow >> 1) & 3)) * 8;
    // read-side swizzled k-chunk
    const int qsw = (quad ^ ((l15 >> 1) & 3)) * 8;
    // Pt swizzle key: row & 7 == l15 & 7 for all Pt accesses
    const int pkey = l15 & 7;

    // ---- prologue: stage Q into KV[1] (16 KB overlay) + K0/V0 into KV[0]
    __bf16* Qst = &KV[1][0][0];   // flat [h][q][32]: h*4096 + q*32 + j
    #pragma unroll
    for (int h = 0; h < 2; h++)
        #pragma unroll
        for (int qq = 0; qq < 2; qq++)
            GLDS16(Qb + (size_t)(q0 + w * 32 + qq * 16 + lrow) * HD + h * 32 + lkof,
                   Qst + h * 4096 + (w * 32 + qq * 16) * 32);
    #pragma unroll
    for (int h = 0; h < 2; h++)
        GLDS16(Kb + (size_t)(w * 16 + lrow) * HD + h * 32 + lkof,
               &KV[0][0][h * 2048 + (w * 16) * 32]);
    #pragma unroll
    for (int kh = 0; kh < 2; kh++)
        GLDS16(Vtb + (size_t)(w * 16 + lrow) * SEQ + kh * 32 + lkof,
               &KV[0][1][kh * 2048 + (w * 16) * 32]);
    __syncthreads();   // all prologue staging visible

    // ---- hoist Q fragments to registers (loop-invariant) ----
    bf16x8 qf[2][2];   // [half][mi]
    #pragma unroll
    for (int h = 0; h < 2; h++)
        #pragma unroll
        for (int mi = 0; mi < 2; mi++)
            qf[h][mi] = *(const bf16x8*)&Qst[h * 4096 +
                          (w * 32 + mi * 16 + l15) * 32 + qsw];
    __syncthreads();   // Q reads done before kt=0 prefetch overwrites KV[1]

    float l_i[2] = {0.0f, 0.0f};
    f32x4 o[2][4];
    #pragma unroll
    for (int mi = 0; mi < 2; mi++)
        #pragma unroll
        for (int db = 0; db < 4; db++) o[mi][db] = (f32x4)0.0f;

    constexpr int NT = SEQ / 64;   // 32 key tiles
    for (int kt = 0; kt < NT; kt++) {
        const int cur = kt & 1, nxt = cur ^ 1;
        if (kt + 1 < NT) {
            const int k0n = (kt + 1) * 64;
            #pragma unroll
            for (int h = 0; h < 2; h++)
                GLDS16(Kb + (size_t)(k0n + w * 16 + lrow) * HD + h * 32 + lkof,
                       &KV[nxt][0][h * 2048 + (w * 16) * 32]);
            #pragma unroll
            for (int kh = 0; kh < 2; kh++)
                GLDS16(Vtb + (size_t)(w * 16 + lrow) * SEQ + k0n + kh * 32 + lkof,
                       &KV[nxt][1][kh * 2048 + (w * 16) * 32]);
        }
        const __bf16* Ks = &KV[cur][0][0];
        const __bf16* Vs = &KV[cur][1][0];

        // ---- S^T = K Q^T : 64k x 32q x 64d per wave (16 MFMAs) ----
        f32x4 st[2][4];
        #pragma unroll
        for (int mi = 0; mi < 2; mi++)
            #pragma unroll
            for (int kb = 0; kb < 4; kb++) st[mi][kb] = (f32x4)0.0f;
        #pragma unroll
        for (int h = 0; h < 2; h++)
            #pragma unroll
            for (int kb = 0; kb < 4; kb++) {
                const bf16x8 kf = *(const bf16x8*)&Ks[h * 2048 +
                                      (kb * 16 + l15) * 32 + qsw];
                #pragma unroll
                for (int mi = 0; mi < 2; mi++)
                    st[mi][kb] = MFMA16(kf, qf[h][mi], st[mi][kb]);
            }

        // ---- fixed-shift softmax: p = exp2(s), accumulate l ----
        #pragma unroll
        for (int mi = 0; mi < 2; mi++) {
            float rs = 0.0f;
            #pragma unroll
            for (int kb = 0; kb < 4; kb++)
                #pragma unroll
                for (int r = 0; r < 4; r++) {
                    const float p = EXP2(st[mi][kb][r]);
                    st[mi][kb][r] = p;
                    rs += p;
                }
            rs += __shfl_xor(rs, 16);
            rs += __shfl_xor(rs, 32);
            l_i[mi] += rs;
            #pragma unroll
            for (int kb = 0; kb < 4; kb++) {
                __bf16 pb[4] = {(__bf16)st[mi][kb][0], (__bf16)st[mi][kb][1],
                                (__bf16)st[mi][kb][2], (__bf16)st[mi][kb][3]};
                // orig elem off = kb*16 + quad*4; 16B chunk = kb*2+(quad>>1),
                // sub-off = (quad&1)*4; swizzle chunk with row key
                const int pc = ((kb * 2 + (quad >> 1)) ^ pkey) * 8 + (quad & 1) * 4;
                *(uint2*)&Pt[w][mi * 16 + l15][pc] = *(uint2*)pb;
            }
        }

        // ---- O^T += V^T P^T : 64d x 32q x 64k per wave (16 MFMAs) ----
        #pragma unroll
        for (int kh = 0; kh < 2; kh++) {
            bf16x8 pf[2];
            #pragma unroll
            for (int mi = 0; mi < 2; mi++) {
                // orig elem off = kh*32 + quad*8; chunk = kh*4+quad
                const int pc = ((kh * 4 + quad) ^ pkey) * 8;
                pf[mi] = *(const bf16x8*)&Pt[w][mi * 16 + l15][pc];
            }
            #pragma unroll
            for (int db = 0; db < 4; db++) {
                const bf16x8 vf = *(const bf16x8*)&Vs[kh * 2048 +
                                      (db * 16 + l15) * 32 + qsw];
                #pragma unroll
                for (int mi = 0; mi < 2; mi++)
                    o[mi][db] = MFMA16(vf, pf[mi], o[mi][db]);
            }
        }

        __syncthreads();   // single barrier: drains prefetch, fences buffers
    }

    // ---- epilogue: normalize, fused subtract-projection, store X2 ----
    const float xs = xsa[0];
    const int b = bh >> 4, h = bh & (NH - 1);
    const __bf16* Vb = V + (size_t)bh * SEQ * HD;
    #pragma unroll
    for (int mi = 0; mi < 2; mi++) {
        const int q = q0 + w * 32 + mi * 16 + l15;   // sequence position
        const float inv = 1.0f / l_i[mi];
        float vv[4][4], on[4][4];
        float dp = 0.0f, nn = 0.0f;
        #pragma unroll
        for (int db = 0; db < 4; db++) {
            __bf16 vb4[4];
            *(uint2*)vb4 = *(const uint2*)&Vb[(size_t)q * HD + db * 16 + quad * 4];
            #pragma unroll
            for (int r = 0; r < 4; r++) {
                const float vf = (float)vb4[r];
                const float of = o[mi][db][r] * inv;
                vv[db][r] = vf;
                on[db][r] = of;
                dp += of * vf;
                nn += vf * vf;
            }
        }
        dp += __shfl_xor(dp, 16); dp += __shfl_xor(dp, 32);
        nn += __shfl_xor(nn, 16); nn += __shfl_xor(nn, 32);
        const float coef = xs * dp / (nn + 1e-8f);
        #pragma unroll
        for (int db = 0; db < 4; db++) {
            __bf16 ob[4];
            #pragma unroll
            for (int r = 0; r < 4; r++)
                ob[r] = (__bf16)(on[db][r] - coef * vv[db][r]);
            *(uint2*)&X2[((size_t)b * SEQ + q) * DM + h * HD + db * 16 + quad * 4] =
                *(uint2*)ob;
        }
    }
}

// ======================================================================
extern "C" void kernel_launch(void* const* d_in, const int* in_sizes, int n_in,
                              void* d_out, int out_size, void* d_ws, size_t ws_size,
                              hipStream_t stream)
{
    (void)in_sizes; (void)n_in; (void)out_size; (void)ws_size;
    const float* x   = (const float*)d_in[0];
    const float* Wq  = (const float*)d_in[1];
    const float* Wk  = (const float*)d_in[2];
    const float* Wv  = (const float*)d_in[3];
    const float* Wo  = (const float*)d_in[4];
    const float* xsa = (const float*)d_in[5];
    float* out = (float*)d_out;

    // workspace layout (bf16 elements): 56 MB total
    __bf16* xb  = (__bf16*)d_ws;        // 4 M
    __bf16* Wb  = xb  + NEL;            // 4 x 1 M (Wq,Wk,Wv,Wo)
    __bf16* Qb  = Wb  + 4 * WEL;        // 4 M  (B,H,S,HD), pre-scaled
    __bf16* Kb  = Qb  + NEL;            // 4 M
    __bf16* Vb  = Kb  + NEL;            // 4 M
    __bf16* Vtb = Vb  + NEL;            // 4 M  (B,H,HD,S)
    __bf16* X2  = Vtb + NEL;            // 4 M  (B,S,DM)

    cvt_x<<<dim3(NEL / 1024), 256, 0, stream>>>(x, xb);
    cvt_w<<<dim3(WEL / 1024, 1, 4), 256, 0, stream>>>(Wq, Wk, Wv, Wo, Wb);

    // Q/K/V projections (V dual-stored to Vt; Q pre-scaled)
    gemm_nt_mfma<128><<<dim3(DM / 128, MROWS / 128, 3), 256, 0, stream>>>(
        xb, Wb, Qb, Vtb, 1);

    // attention + fused subtract-projection -> X2 (1D XCD-pinned grid)
    attn_mfma<<<dim3((SEQ / 128) * BATCH * NH), 256, 0, stream>>>(
        Qb, Kb, Vtb, Vb, xsa, X2);

    // output projection (BN=64 -> 512 blocks for occupancy), fp32 out
    gemm_nt_mfma<64><<<dim3(DM / 64, MROWS / 128, 1), 256, 0, stream>>>(
        X2, Wb + 3 * WEL, out, nullptr, 0);
}

// Round 4
// 197.350 us; speedup vs baseline: 1.0385x; 1.0069x over previous
//
#include <hip/hip_runtime.h>
#include <math.h>

// Problem constants
#define BATCH 2
#define SEQ   2048
#define NH    16
#define HD    64
#define DM    1024
#define MROWS (BATCH * SEQ)                  // 4096
#define NEL   ((size_t)MROWS * DM)           // 4 M elements (activation buffer)
#define WEL   ((size_t)DM * DM)              // 1 M elements (weight buffer)
// softmax scale folded into Q at projection: 1/sqrt(64) * log2(e)
#define SM_SCALE_LOG2E 0.18033688011112042f

typedef __bf16 bf16x8 __attribute__((ext_vector_type(8)));
typedef float  f32x4  __attribute__((ext_vector_type(4)));

#define MFMA16(a, b, c) __builtin_amdgcn_mfma_f32_16x16x32_bf16((a), (b), (c), 0, 0, 0)
#define EXP2(x) __builtin_amdgcn_exp2f(x)

// async global->LDS, 16B per lane; LDS dest = wave-uniform base + lane*16
#define GLDS16(g, s) __builtin_amdgcn_global_load_lds( \
    (const __attribute__((address_space(1))) void*)(g), \
    (__attribute__((address_space(3))) void*)(s), 16, 0, 0)

// ----------------------------------------------------------------------
// LDS swizzles (verified R2/R3): K/V/Q tiles [row][32] use chunk' =
// chunk ^ ((row>>1)&3) staged via pre-swizzled GLOBAL source column;
// Pt [row][64] uses 16B-chunk ^ (row&7) on write and read.
// Conflicts: 7.37M -> 3.15M -> 2.1M (rest = shfl ds_swizzles + GLDS
// write accounting; not addressable by layout).
// XCD pinning (verified R3): 1D grid with bh = id&31 -> id%8 == bh%8,
// all q-tiles of one (b,h) on one XCD; FETCH 73.8 MB -> 16.4 MB.
// ----------------------------------------------------------------------

// ======================================================================
// fp32 -> bf16 convert, single launch: blocks [0,4096) convert x,
// blocks [4096,8192) convert the 4 weight matrices.
// ======================================================================
__global__ __launch_bounds__(256) void cvt_all(
    const float* __restrict__ x,
    const float* __restrict__ w0, const float* __restrict__ w1,
    const float* __restrict__ w2, const float* __restrict__ w3,
    __bf16* __restrict__ xb, __bf16* __restrict__ wb)
{
    const int bid = blockIdx.x;
    const float* src;
    __bf16* dst;
    size_t base;
    if (bid < 4096) {
        src = x; dst = xb; base = (size_t)bid * 1024;
    } else {
        const int r = bid - 4096;
        const int z = r >> 10;
        src = (z == 0) ? w0 : (z == 1) ? w1 : (z == 2) ? w2 : w3;
        dst = wb + (size_t)z * WEL;
        base = (size_t)(r & 1023) * 1024;
    }
    const size_t i = base + (size_t)threadIdx.x * 4;
    const float4 f = *(const float4*)&src[i];
    __bf16 b[4] = {(__bf16)f.x, (__bf16)f.y, (__bf16)f.z, (__bf16)f.w};
    *(ushort4*)&dst[i] = *(ushort4*)b;
}

// ======================================================================
// NT bf16 MFMA GEMM, single-barrier double-buffered K-loop.
// C[m,n] = sum_k A[m,k]*W[n,k]. Tile 128 x BN, BK=32, 4 waves.
// LDS k-chunk XOR-swizzled -> conflict-free b128 fragment reads.
// mode 1 (BN=128): z selects weight+output slab; bf16 store permuted to
//   (B,H,S,HD); z==0 (Q) pre-scaled; z==2 (V) dual-stored to Vt.
// mode 0: fp32 row-major M x DM store.
// ======================================================================
template<int BN>
__global__ __launch_bounds__(256) void gemm_nt_mfma(
    const __bf16* __restrict__ A, const __bf16* __restrict__ W0,
    void* __restrict__ C0, __bf16* __restrict__ Vt, int mode)
{
    constexpr int NI  = BN / 32;         // 16-col groups per wave
    constexpr int NIT = DM / 32;         // 32 K-iterations
    __shared__ __bf16 Ast[2][128 * 32];
    __shared__ __bf16 Bst[2][BN * 32];

    const int t = threadIdx.x;
    const int w = t >> 6, l = t & 63;
    const int quad = l >> 4, l15 = l & 15;
    const int z = blockIdx.z;
    const int m0 = blockIdx.y * 128, n0 = blockIdx.x * BN;
    const int wm = (w >> 1) * 64, wn = (w & 1) * (BN / 2);

    const __bf16* Wp = W0 + (size_t)z * WEL;

    const int lrow = l >> 2;           // staging: lane row within 16-row instr
    // staging k-offset: pre-swizzled global source column (rule #21)
    const int lkof = ((l & 3) ^ ((lrow >> 1) & 3)) * 8;
    // read-side swizzled k-chunk (row bits 1..2 == l15 bits 1..2)
    const int qsw = (quad ^ ((l15 >> 1) & 3)) * 8;

    const __bf16* Ag = A + (size_t)(m0 + w * 32 + lrow) * DM + lkof;
    const int aoff = (w * 32) * 32;    // wave-uniform LDS offset (A)
    // B staging: BN=128 -> 2 instrs/wave (rows w*32); BN=64 -> 1 (rows w*16)
    const int brow = (BN == 128) ? (w * 32) : (w * 16);
    const __bf16* Bg = Wp + (size_t)(n0 + brow + lrow) * DM + lkof;
    const int boff = brow * 32;

    f32x4 acc[4][NI];
    #pragma unroll
    for (int i = 0; i < 4; i++)
        #pragma unroll
        for (int j = 0; j < NI; j++) acc[i][j] = (f32x4)0.0f;

    // prologue: tile 0 -> buf 0
    GLDS16(Ag,           &Ast[0][aoff]);
    GLDS16(Ag + 16 * DM, &Ast[0][aoff + 512]);
    GLDS16(Bg,           &Bst[0][boff]);
    if (BN == 128) GLDS16(Bg + 16 * DM, &Bst[0][boff + 512]);
    __syncthreads();

    for (int i = 0; i < NIT; i++) {
        const int cur = i & 1, nxt = cur ^ 1;
        if (i + 1 < NIT) {
            const int k0 = (i + 1) * 32;
            GLDS16(Ag + k0,           &Ast[nxt][aoff]);
            GLDS16(Ag + k0 + 16 * DM, &Ast[nxt][aoff + 512]);
            GLDS16(Bg + k0,           &Bst[nxt][boff]);
            if (BN == 128) GLDS16(Bg + k0 + 16 * DM, &Bst[nxt][boff + 512]);
        }

        bf16x8 af[4], bfr[NI];
        #pragma unroll
        for (int mi = 0; mi < 4; mi++)
            af[mi] = *(const bf16x8*)&Ast[cur][(wm + mi * 16 + l15) * 32 + qsw];
        #pragma unroll
        for (int ni = 0; ni < NI; ni++)
            bfr[ni] = *(const bf16x8*)&Bst[cur][(wn + ni * 16 + l15) * 32 + qsw];
        __builtin_amdgcn_s_setprio(1);
        #pragma unroll
        for (int mi = 0; mi < 4; mi++)
            #pragma unroll
            for (int ni = 0; ni < NI; ni++)
                acc[mi][ni] = MFMA16(af[mi], bfr[ni], acc[mi][ni]);
        __builtin_amdgcn_s_setprio(0);

        __syncthreads();   // single barrier: drains prefetch, fences buffers
    }

    if (mode) {
        const float sc = (z == 0) ? SM_SCALE_LOG2E : 1.0f;
        __bf16* C = (__bf16*)C0 + (size_t)z * NEL;
        #pragma unroll
        for (int mi = 0; mi < 4; mi++)
            #pragma unroll
            for (int ni = 0; ni < NI; ni++)
                #pragma unroll
                for (int r = 0; r < 4; r++) {
                    const int row = m0 + wm + mi * 16 + quad * 4 + r;
                    const int col = n0 + wn + ni * 16 + l15;
                    const int b = row >> 11, s = row & (SEQ - 1);
                    const int h = col >> 6,  d = col & (HD - 1);
                    const __bf16 val = (__bf16)(acc[mi][ni][r] * sc);
                    C[((size_t)(b * NH + h) * SEQ + s) * HD + d] = val;
                    if (z == 2)   // V: also store transposed (B,H,HD,S)
                        Vt[((size_t)(b * NH + h) * HD + d) * SEQ + s] = val;
                }
    } else {
        float* C = (float*)C0;
        #pragma unroll
        for (int mi = 0; mi < 4; mi++)
            #pragma unroll
            for (int ni = 0; ni < NI; ni++)
                #pragma unroll
                for (int r = 0; r < 4; r++) {
                    const int row = m0 + wm + mi * 16 + quad * 4 + r;
                    const int col = n0 + wn + ni * 16 + l15;
                    C[(size_t)row * DM + col] = acc[mi][ni][r];
                }
    }
}

// ======================================================================
// Flash attention v7: v6 + 2-wave/64q blocks + s_setprio on MFMA.
//  - Block = 64 queries, 2 waves (128 thr), 32 q/wave (inner loop
//    identical to v6). Grid = 1024 -> 4 independent blocks/CU (LDS
//    40 KB x 4 = 160 KB exact). Same 8 waves/CU, but barrier domains
//    2 -> 4 and waves-per-barrier 4 -> 2: per-tile prefetch drains on
//    one block overlap with compute on three others.
//  - s_setprio(1) around QK^T and PV MFMA clusters (T5).
//  - XCD pinning kept: bh = id & 31 -> id%8 == bh%8.
// LDS: KV dbuf 32 KB + Pt 8 KB = 40 KB.
// ======================================================================
__global__ __launch_bounds__(128, 2) void attn_mfma(
    const __bf16* __restrict__ Q, const __bf16* __restrict__ K,
    const __bf16* __restrict__ Vt, const __bf16* __restrict__ V,
    const float* __restrict__ xsa, __bf16* __restrict__ X2)
{
    // KV[buf][0] = K region [half][key][32]; KV[buf][1] = V region
    // [keyhalf][dim][32]. Each region 4096 elems (8 KB).
    __shared__ __bf16 KV[2][2][2 * 64 * 32];
    __shared__ __bf16 Pt[2][32][64];   // per-wave P [q][key], XOR-swizzled

    const int t = threadIdx.x;
    const int w = t >> 6, l = t & 63;   // w in {0,1}
    const int quad = l >> 4, l15 = l & 15;
    // XCD-pinned decomposition: id%8 == bh%8 -> one XCD per (b,h)
    const int bh = blockIdx.x & 31;
    const int q0 = (blockIdx.x >> 5) * 64;

    const __bf16* Qb  = Q  + (size_t)bh * SEQ * HD;
    const __bf16* Kb  = K  + (size_t)bh * SEQ * HD;
    const __bf16* Vtb = Vt + (size_t)bh * HD * SEQ;

    const int lrow = l >> 2;
    // staging k-offset: pre-swizzled global source column (rule #21)
    const int lkof = ((l & 3) ^ ((lrow >> 1) & 3)) * 8;
    // read-side swizzled k-chunk
    const int qsw = (quad ^ ((l15 >> 1) & 3)) * 8;
    // Pt swizzle key: row & 7 == l15 & 7 for all Pt accesses
    const int pkey = l15 & 7;

    // ---- prologue: stage Q into KV[1] (8 KB overlay) + K0/V0 into KV[0]
    __bf16* Qst = &KV[1][0][0];   // flat [h][q][32]: h*2048 + q*32 + j
    #pragma unroll
    for (int h = 0; h < 2; h++)
        #pragma unroll
        for (int qq = 0; qq < 2; qq++)
            GLDS16(Qb + (size_t)(q0 + w * 32 + qq * 16 + lrow) * HD + h * 32 + lkof,
                   Qst + h * 2048 + (w * 32 + qq * 16) * 32);
    #pragma unroll
    for (int h = 0; h < 2; h++)
        #pragma unroll
        for (int qq = 0; qq < 2; qq++)
            GLDS16(Kb + (size_t)(w * 32 + qq * 16 + lrow) * HD + h * 32 + lkof,
                   &KV[0][0][h * 2048 + (w * 32 + qq * 16) * 32]);
    #pragma unroll
    for (int kh = 0; kh < 2; kh++)
        #pragma unroll
        for (int qq = 0; qq < 2; qq++)
            GLDS16(Vtb + (size_t)(w * 32 + qq * 16 + lrow) * SEQ + kh * 32 + lkof,
                   &KV[0][1][kh * 2048 + (w * 32 + qq * 16) * 32]);
    __syncthreads();   // all prologue staging visible

    // ---- hoist Q fragments to registers (loop-invariant) ----
    bf16x8 qf[2][2];   // [half][mi]
    #pragma unroll
    for (int h = 0; h < 2; h++)
        #pragma unroll
        for (int mi = 0; mi < 2; mi++)
            qf[h][mi] = *(const bf16x8*)&Qst[h * 2048 +
                          (w * 32 + mi * 16 + l15) * 32 + qsw];
    __syncthreads();   // Q reads done before kt=0 prefetch overwrites KV[1]

    float l_i[2] = {0.0f, 0.0f};
    f32x4 o[2][4];
    #pragma unroll
    for (int mi = 0; mi < 2; mi++)
        #pragma unroll
        for (int db = 0; db < 4; db++) o[mi][db] = (f32x4)0.0f;

    constexpr int NT = SEQ / 64;   // 32 key tiles
    for (int kt = 0; kt < NT; kt++) {
        const int cur = kt & 1, nxt = cur ^ 1;
        if (kt + 1 < NT) {
            const int k0n = (kt + 1) * 64;
            #pragma unroll
            for (int h = 0; h < 2; h++)
                #pragma unroll
                for (int qq = 0; qq < 2; qq++)
                    GLDS16(Kb + (size_t)(k0n + w * 32 + qq * 16 + lrow) * HD + h * 32 + lkof,
                           &KV[nxt][0][h * 2048 + (w * 32 + qq * 16) * 32]);
            #pragma unroll
            for (int kh = 0; kh < 2; kh++)
                #pragma unroll
                for (int qq = 0; qq < 2; qq++)
                    GLDS16(Vtb + (size_t)(w * 32 + qq * 16 + lrow) * SEQ + k0n + kh * 32 + lkof,
                           &KV[nxt][1][kh * 2048 + (w * 32 + qq * 16) * 32]);
        }
        const __bf16* Ks = &KV[cur][0][0];
        const __bf16* Vs = &KV[cur][1][0];

        // ---- S^T = K Q^T : 64k x 32q x 64d per wave (16 MFMAs) ----
        f32x4 st[2][4];
        #pragma unroll
        for (int mi = 0; mi < 2; mi++)
            #pragma unroll
            for (int kb = 0; kb < 4; kb++) st[mi][kb] = (f32x4)0.0f;
        __builtin_amdgcn_s_setprio(1);
        #pragma unroll
        for (int h = 0; h < 2; h++)
            #pragma unroll
            for (int kb = 0; kb < 4; kb++) {
                const bf16x8 kf = *(const bf16x8*)&Ks[h * 2048 +
                                      (kb * 16 + l15) * 32 + qsw];
                #pragma unroll
                for (int mi = 0; mi < 2; mi++)
                    st[mi][kb] = MFMA16(kf, qf[h][mi], st[mi][kb]);
            }
        __builtin_amdgcn_s_setprio(0);

        // ---- fixed-shift softmax: p = exp2(s), accumulate l ----
        #pragma unroll
        for (int mi = 0; mi < 2; mi++) {
            float rs = 0.0f;
            #pragma unroll
            for (int kb = 0; kb < 4; kb++)
                #pragma unroll
                for (int r = 0; r < 4; r++) {
                    const float p = EXP2(st[mi][kb][r]);
                    st[mi][kb][r] = p;
                    rs += p;
                }
            rs += __shfl_xor(rs, 16);
            rs += __shfl_xor(rs, 32);
            l_i[mi] += rs;
            #pragma unroll
            for (int kb = 0; kb < 4; kb++) {
                __bf16 pb[4] = {(__bf16)st[mi][kb][0], (__bf16)st[mi][kb][1],
                                (__bf16)st[mi][kb][2], (__bf16)st[mi][kb][3]};
                // orig elem off = kb*16 + quad*4; 16B chunk = kb*2+(quad>>1),
                // sub-off = (quad&1)*4; swizzle chunk with row key
                const int pc = ((kb * 2 + (quad >> 1)) ^ pkey) * 8 + (quad & 1) * 4;
                *(uint2*)&Pt[w][mi * 16 + l15][pc] = *(uint2*)pb;
            }
        }

        // ---- O^T += V^T P^T : 64d x 32q x 64k per wave (16 MFMAs) ----
        #pragma unroll
        for (int kh = 0; kh < 2; kh++) {
            bf16x8 pf[2];
            #pragma unroll
            for (int mi = 0; mi < 2; mi++) {
                // orig elem off = kh*32 + quad*8; chunk = kh*4+quad
                const int pc = ((kh * 4 + quad) ^ pkey) * 8;
                pf[mi] = *(const bf16x8*)&Pt[w][mi * 16 + l15][pc];
            }
            __builtin_amdgcn_s_setprio(1);
            #pragma unroll
            for (int db = 0; db < 4; db++) {
                const bf16x8 vf = *(const bf16x8*)&Vs[kh * 2048 +
                                      (db * 16 + l15) * 32 + qsw];
                #pragma unroll
                for (int mi = 0; mi < 2; mi++)
                    o[mi][db] = MFMA16(vf, pf[mi], o[mi][db]);
            }
            __builtin_amdgcn_s_setprio(0);
        }

        __syncthreads();   // single barrier: drains prefetch, fences buffers
    }

    // ---- epilogue: normalize, fused subtract-projection, store X2 ----
    const float xs = xsa[0];
    const int b = bh >> 4, h = bh & (NH - 1);
    const __bf16* Vb = V + (size_t)bh * SEQ * HD;
    #pragma unroll
    for (int mi = 0; mi < 2; mi++) {
        const int q = q0 + w * 32 + mi * 16 + l15;   // sequence position
        const float inv = 1.0f / l_i[mi];
        float vv[4][4], on[4][4];
        float dp = 0.0f, nn = 0.0f;
        #pragma unroll
        for (int db = 0; db < 4; db++) {
            __bf16 vb4[4];
            *(uint2*)vb4 = *(const uint2*)&Vb[(size_t)q * HD + db * 16 + quad * 4];
            #pragma unroll
            for (int r = 0; r < 4; r++) {
                const float vf = (float)vb4[r];
                const float of = o[mi][db][r] * inv;
                vv[db][r] = vf;
                on[db][r] = of;
                dp += of * vf;
                nn += vf * vf;
            }
        }
        dp += __shfl_xor(dp, 16); dp += __shfl_xor(dp, 32);
        nn += __shfl_xor(nn, 16); nn += __shfl_xor(nn, 32);
        const float coef = xs * dp / (nn + 1e-8f);
        #pragma unroll
        for (int db = 0; db < 4; db++) {
            __bf16 ob[4];
            #pragma unroll
            for (int r = 0; r < 4; r++)
                ob[r] = (__bf16)(on[db][r] - coef * vv[db][r]);
            *(uint2*)&X2[((size_t)b * SEQ + q) * DM + h * HD + db * 16 + quad * 4] =
                *(uint2*)ob;
        }
    }
}

// ======================================================================
extern "C" void kernel_launch(void* const* d_in, const int* in_sizes, int n_in,
                              void* d_out, int out_size, void* d_ws, size_t ws_size,
                              hipStream_t stream)
{
    (void)in_sizes; (void)n_in; (void)out_size; (void)ws_size;
    const float* x   = (const float*)d_in[0];
    const float* Wq  = (const float*)d_in[1];
    const float* Wk  = (const float*)d_in[2];
    const float* Wv  = (const float*)d_in[3];
    const float* Wo  = (const float*)d_in[4];
    const float* xsa = (const float*)d_in[5];
    float* out = (float*)d_out;

    // workspace layout (bf16 elements): 56 MB total
    __bf16* xb  = (__bf16*)d_ws;        // 4 M
    __bf16* Wb  = xb  + NEL;            // 4 x 1 M (Wq,Wk,Wv,Wo)
    __bf16* Qb  = Wb  + 4 * WEL;        // 4 M  (B,H,S,HD), pre-scaled
    __bf16* Kb  = Qb  + NEL;            // 4 M
    __bf16* Vb  = Kb  + NEL;            // 4 M
    __bf16* Vtb = Vb  + NEL;            // 4 M  (B,H,HD,S)
    __bf16* X2  = Vtb + NEL;            // 4 M  (B,S,DM)

    // all fp32->bf16 conversions in one launch
    cvt_all<<<dim3(8192), 256, 0, stream>>>(x, Wq, Wk, Wv, Wo, xb, Wb);

    // Q/K/V projections (V dual-stored to Vt; Q pre-scaled)
    gemm_nt_mfma<128><<<dim3(DM / 128, MROWS / 128, 3), 256, 0, stream>>>(
        xb, Wb, Qb, Vtb, 1);

    // attention + fused subtract-projection -> X2 (1D XCD-pinned grid,
    // 64q / 2-wave blocks)
    attn_mfma<<<dim3((SEQ / 64) * BATCH * NH), 128, 0, stream>>>(
        Qb, Kb, Vtb, Vb, xsa, X2);

    // output projection (BN=64 -> 512 blocks for occupancy), fp32 out
    gemm_nt_mfma<64><<<dim3(DM / 64, MROWS / 128, 1), 256, 0, stream>>>(
        X2, Wb + 3 * WEL, out, nullptr, 0);
}

// Round 5
// 192.017 us; speedup vs baseline: 1.0673x; 1.0278x over previous
//
#include <hip/hip_runtime.h>
#include <math.h>

// Problem constants
#define BATCH 2
#define SEQ   2048
#define NH    16
#define HD    64
#define DM    1024
#define MROWS (BATCH * SEQ)                  // 4096
#define NEL   ((size_t)MROWS * DM)           // 4 M elements (activation buffer)
#define WEL   ((size_t)DM * DM)              // 1 M elements (weight buffer)
// softmax scale folded into Q at projection: 1/sqrt(64) * log2(e)
#define SM_SCALE_LOG2E 0.18033688011112042f

typedef __bf16 bf16x8 __attribute__((ext_vector_type(8)));
typedef float  f32x4  __attribute__((ext_vector_type(4)));

#define MFMA16(a, b, c) __builtin_amdgcn_mfma_f32_16x16x32_bf16((a), (b), (c), 0, 0, 0)
#define EXP2(x) __builtin_amdgcn_exp2f(x)

// async global->LDS, 16B per lane; LDS dest = wave-uniform base + lane*16
#define GLDS16(g, s) __builtin_amdgcn_global_load_lds( \
    (const __attribute__((address_space(1))) void*)(g), \
    (__attribute__((address_space(3))) void*)(s), 16, 0, 0)

// ----------------------------------------------------------------------
// LDS swizzles (verified R2/R3): K/V/Q tiles [row][32] use chunk' =
// chunk ^ ((row>>1)&3) staged via pre-swizzled GLOBAL source column;
// Pt [row][64] uses 16B-chunk ^ (row&7) on write and read.
// XCD pinning (verified R3): bh = id&31 -> id%8 == bh%8; FETCH 74->16 MB.
// R4 lesson: 2-wave/64q blocks double K/V streaming, regress attn 58->62;
// revert to 4-wave/128q. This round: KVBLK 64->128 (barriers 32->16;
// per-wave Pt sub-phased, no intra-tile sync) + l_i reduction deferred
// to epilogue (removes in-loop ds_swizzle chains).
// ----------------------------------------------------------------------

// ======================================================================
// fp32 -> bf16 convert, single launch: blocks [0,4096) convert x,
// blocks [4096,8192) convert the 4 weight matrices.
// ======================================================================
__global__ __launch_bounds__(256) void cvt_all(
    const float* __restrict__ x,
    const float* __restrict__ w0, const float* __restrict__ w1,
    const float* __restrict__ w2, const float* __restrict__ w3,
    __bf16* __restrict__ xb, __bf16* __restrict__ wb)
{
    const int bid = blockIdx.x;
    const float* src;
    __bf16* dst;
    size_t base;
    if (bid < 4096) {
        src = x; dst = xb; base = (size_t)bid * 1024;
    } else {
        const int r = bid - 4096;
        const int z = r >> 10;
        src = (z == 0) ? w0 : (z == 1) ? w1 : (z == 2) ? w2 : w3;
        dst = wb + (size_t)z * WEL;
        base = (size_t)(r & 1023) * 1024;
    }
    const size_t i = base + (size_t)threadIdx.x * 4;
    const float4 f = *(const float4*)&src[i];
    __bf16 b[4] = {(__bf16)f.x, (__bf16)f.y, (__bf16)f.z, (__bf16)f.w};
    *(ushort4*)&dst[i] = *(ushort4*)b;
}

// ======================================================================
// NT bf16 MFMA GEMM, single-barrier double-buffered K-loop.
// C[m,n] = sum_k A[m,k]*W[n,k]. Tile 128 x BN, BK=32, 4 waves.
// LDS k-chunk XOR-swizzled -> conflict-free b128 fragment reads.
// mode 1 (BN=128): z selects weight+output slab; bf16 store permuted to
//   (B,H,S,HD); z==0 (Q) pre-scaled; z==2 (V) dual-stored to Vt.
// mode 0: fp32 row-major M x DM store.
// ======================================================================
template<int BN>
__global__ __launch_bounds__(256) void gemm_nt_mfma(
    const __bf16* __restrict__ A, const __bf16* __restrict__ W0,
    void* __restrict__ C0, __bf16* __restrict__ Vt, int mode)
{
    constexpr int NI  = BN / 32;         // 16-col groups per wave
    constexpr int NIT = DM / 32;         // 32 K-iterations
    __shared__ __bf16 Ast[2][128 * 32];
    __shared__ __bf16 Bst[2][BN * 32];

    const int t = threadIdx.x;
    const int w = t >> 6, l = t & 63;
    const int quad = l >> 4, l15 = l & 15;
    const int z = blockIdx.z;
    const int m0 = blockIdx.y * 128, n0 = blockIdx.x * BN;
    const int wm = (w >> 1) * 64, wn = (w & 1) * (BN / 2);

    const __bf16* Wp = W0 + (size_t)z * WEL;

    const int lrow = l >> 2;           // staging: lane row within 16-row instr
    // staging k-offset: pre-swizzled global source column (rule #21)
    const int lkof = ((l & 3) ^ ((lrow >> 1) & 3)) * 8;
    // read-side swizzled k-chunk (row bits 1..2 == l15 bits 1..2)
    const int qsw = (quad ^ ((l15 >> 1) & 3)) * 8;

    const __bf16* Ag = A + (size_t)(m0 + w * 32 + lrow) * DM + lkof;
    const int aoff = (w * 32) * 32;    // wave-uniform LDS offset (A)
    // B staging: BN=128 -> 2 instrs/wave (rows w*32); BN=64 -> 1 (rows w*16)
    const int brow = (BN == 128) ? (w * 32) : (w * 16);
    const __bf16* Bg = Wp + (size_t)(n0 + brow + lrow) * DM + lkof;
    const int boff = brow * 32;

    f32x4 acc[4][NI];
    #pragma unroll
    for (int i = 0; i < 4; i++)
        #pragma unroll
        for (int j = 0; j < NI; j++) acc[i][j] = (f32x4)0.0f;

    // prologue: tile 0 -> buf 0
    GLDS16(Ag,           &Ast[0][aoff]);
    GLDS16(Ag + 16 * DM, &Ast[0][aoff + 512]);
    GLDS16(Bg,           &Bst[0][boff]);
    if (BN == 128) GLDS16(Bg + 16 * DM, &Bst[0][boff + 512]);
    __syncthreads();

    for (int i = 0; i < NIT; i++) {
        const int cur = i & 1, nxt = cur ^ 1;
        if (i + 1 < NIT) {
            const int k0 = (i + 1) * 32;
            GLDS16(Ag + k0,           &Ast[nxt][aoff]);
            GLDS16(Ag + k0 + 16 * DM, &Ast[nxt][aoff + 512]);
            GLDS16(Bg + k0,           &Bst[nxt][boff]);
            if (BN == 128) GLDS16(Bg + k0 + 16 * DM, &Bst[nxt][boff + 512]);
        }

        bf16x8 af[4], bfr[NI];
        #pragma unroll
        for (int mi = 0; mi < 4; mi++)
            af[mi] = *(const bf16x8*)&Ast[cur][(wm + mi * 16 + l15) * 32 + qsw];
        #pragma unroll
        for (int ni = 0; ni < NI; ni++)
            bfr[ni] = *(const bf16x8*)&Bst[cur][(wn + ni * 16 + l15) * 32 + qsw];
        __builtin_amdgcn_s_setprio(1);
        #pragma unroll
        for (int mi = 0; mi < 4; mi++)
            #pragma unroll
            for (int ni = 0; ni < NI; ni++)
                acc[mi][ni] = MFMA16(af[mi], bfr[ni], acc[mi][ni]);
        __builtin_amdgcn_s_setprio(0);

        __syncthreads();   // single barrier: drains prefetch, fences buffers
    }

    if (mode) {
        const float sc = (z == 0) ? SM_SCALE_LOG2E : 1.0f;
        __bf16* C = (__bf16*)C0 + (size_t)z * NEL;
        #pragma unroll
        for (int mi = 0; mi < 4; mi++)
            #pragma unroll
            for (int ni = 0; ni < NI; ni++)
                #pragma unroll
                for (int r = 0; r < 4; r++) {
                    const int row = m0 + wm + mi * 16 + quad * 4 + r;
                    const int col = n0 + wn + ni * 16 + l15;
                    const int b = row >> 11, s = row & (SEQ - 1);
                    const int h = col >> 6,  d = col & (HD - 1);
                    const __bf16 val = (__bf16)(acc[mi][ni][r] * sc);
                    C[((size_t)(b * NH + h) * SEQ + s) * HD + d] = val;
                    if (z == 2)   // V: also store transposed (B,H,HD,S)
                        Vt[((size_t)(b * NH + h) * HD + d) * SEQ + s] = val;
                }
    } else {
        float* C = (float*)C0;
        #pragma unroll
        for (int mi = 0; mi < 4; mi++)
            #pragma unroll
            for (int ni = 0; ni < NI; ni++)
                #pragma unroll
                for (int r = 0; r < 4; r++) {
                    const int row = m0 + wm + mi * 16 + quad * 4 + r;
                    const int col = n0 + wn + ni * 16 + l15;
                    C[(size_t)row * DM + col] = acc[mi][ni][r];
                }
    }
}

// ======================================================================
// Flash attention v8: R3's 4-wave/128q structure + KVBLK=128 + deferred
// l_i reduction.
//  - KVBLK=128: one barrier per 128 keys (16 iterations). Inside each
//    iteration, two 64-key sub-phases share the per-wave Pt buffer with
//    NO sync (wave-serial reuse; compiler orders via lgkmcnt).
//  - l_i: per-lane partial in-loop (covers this lane's keys only);
//    quad-reduce once in epilogue. Removes 4 ds_swizzle/tile from loop.
//  - XCD-pinned 1D grid (bh = id&31), swizzled K/V/Q + Pt, setprio on
//    MFMA clusters.
// Block = 128 queries of one (b,h), 4 waves, 32 q/wave.
// LDS: KV dbuf 2 x 32 KB + Pt 16 KB = 80 KB -> 2 blocks/CU (grid 512).
// ======================================================================
__global__ __launch_bounds__(256, 2) void attn_mfma(
    const __bf16* __restrict__ Q, const __bf16* __restrict__ K,
    const __bf16* __restrict__ Vt, const __bf16* __restrict__ V,
    const float* __restrict__ xsa, __bf16* __restrict__ X2)
{
    // KV[buf][0] = K region [h][key128][32]  (h*4096 + key*32 + j)
    // KV[buf][1] = V region [kg][dim64][32]  (kg*2048 + dim*32 + j), kg=key/32
    __shared__ __bf16 KV[2][2][8192];
    __shared__ __bf16 Pt[4][32][64];   // per-wave P [q][key64], XOR-swizzled

    const int t = threadIdx.x;
    const int w = t >> 6, l = t & 63;
    const int quad = l >> 4, l15 = l & 15;
    // XCD-pinned decomposition: id%8 == bh%8 -> one XCD per (b,h)
    const int bh = blockIdx.x & 31;
    const int q0 = (blockIdx.x >> 5) * 128;

    const __bf16* Qb  = Q  + (size_t)bh * SEQ * HD;
    const __bf16* Kb  = K  + (size_t)bh * SEQ * HD;
    const __bf16* Vtb = Vt + (size_t)bh * HD * SEQ;

    const int lrow = l >> 2;
    // staging k-offset: pre-swizzled global source column (rule #21)
    const int lkof = ((l & 3) ^ ((lrow >> 1) & 3)) * 8;
    // read-side swizzled k-chunk
    const int qsw = (quad ^ ((l15 >> 1) & 3)) * 8;
    // Pt swizzle key: row & 7 == l15 & 7 for all Pt accesses
    const int pkey = l15 & 7;

    // ---- prologue: stage Q into KV[1][0] (16 KB overlay) + K0/V0 -> KV[0]
    __bf16* Qst = &KV[1][0][0];   // flat [h][q128][32]: h*4096 + q*32 + j
    #pragma unroll
    for (int h = 0; h < 2; h++)
        #pragma unroll
        for (int qq = 0; qq < 2; qq++)
            GLDS16(Qb + (size_t)(q0 + w * 32 + qq * 16 + lrow) * HD + h * 32 + lkof,
                   Qst + h * 4096 + (w * 32 + qq * 16) * 32);
    #pragma unroll
    for (int h = 0; h < 2; h++)
        #pragma unroll
        for (int qq = 0; qq < 2; qq++)
            GLDS16(Kb + (size_t)(w * 32 + qq * 16 + lrow) * HD + h * 32 + lkof,
                   &KV[0][0][h * 4096 + (w * 32 + qq * 16) * 32]);
    #pragma unroll
    for (int kg = 0; kg < 4; kg++)
        GLDS16(Vtb + (size_t)(w * 16 + lrow) * SEQ + kg * 32 + lkof,
               &KV[0][1][kg * 2048 + (w * 16) * 32]);
    __syncthreads();   // all prologue staging visible

    // ---- hoist Q fragments to registers (loop-invariant) ----
    bf16x8 qf[2][2];   // [half][mi]
    #pragma unroll
    for (int h = 0; h < 2; h++)
        #pragma unroll
        for (int mi = 0; mi < 2; mi++)
            qf[h][mi] = *(const bf16x8*)&Qst[h * 4096 +
                          (w * 32 + mi * 16 + l15) * 32 + qsw];
    __syncthreads();   // Q reads done before kt=0 prefetch overwrites KV[1]

    float l_i[2] = {0.0f, 0.0f};   // per-lane partials; reduced in epilogue
    f32x4 o[2][4];
    #pragma unroll
    for (int mi = 0; mi < 2; mi++)
        #pragma unroll
        for (int db = 0; db < 4; db++) o[mi][db] = (f32x4)0.0f;

    constexpr int NT = SEQ / 128;   // 16 key tiles of 128
    for (int kt = 0; kt < NT; kt++) {
        const int cur = kt & 1, nxt = cur ^ 1;
        if (kt + 1 < NT) {
            const int k0n = (kt + 1) * 128;
            #pragma unroll
            for (int h = 0; h < 2; h++)
                #pragma unroll
                for (int qq = 0; qq < 2; qq++)
                    GLDS16(Kb + (size_t)(k0n + w * 32 + qq * 16 + lrow) * HD + h * 32 + lkof,
                           &KV[nxt][0][h * 4096 + (w * 32 + qq * 16) * 32]);
            #pragma unroll
            for (int kg = 0; kg < 4; kg++)
                GLDS16(Vtb + (size_t)(w * 16 + lrow) * SEQ + k0n + kg * 32 + lkof,
                       &KV[nxt][1][kg * 2048 + (w * 16) * 32]);
        }
        const __bf16* Ks = &KV[cur][0][0];
        const __bf16* Vs = &KV[cur][1][0];

        // two 64-key sub-phases; per-wave Pt reused with no block sync
        #pragma unroll
        for (int sub = 0; sub < 2; sub++) {
            // ---- S^T = K Q^T : 64k x 32q x 64d per wave (16 MFMAs) ----
            f32x4 st[2][4];
            #pragma unroll
            for (int mi = 0; mi < 2; mi++)
                #pragma unroll
                for (int kb = 0; kb < 4; kb++) st[mi][kb] = (f32x4)0.0f;
            __builtin_amdgcn_s_setprio(1);
            #pragma unroll
            for (int h = 0; h < 2; h++)
                #pragma unroll
                for (int kb = 0; kb < 4; kb++) {
                    const bf16x8 kf = *(const bf16x8*)&Ks[h * 4096 +
                                          (sub * 64 + kb * 16 + l15) * 32 + qsw];
                    #pragma unroll
                    for (int mi = 0; mi < 2; mi++)
                        st[mi][kb] = MFMA16(kf, qf[h][mi], st[mi][kb]);
                }
            __builtin_amdgcn_s_setprio(0);

            // ---- fixed-shift softmax: p = exp2(s), per-lane l partial ----
            #pragma unroll
            for (int mi = 0; mi < 2; mi++) {
                float rs = 0.0f;
                #pragma unroll
                for (int kb = 0; kb < 4; kb++)
                    #pragma unroll
                    for (int r = 0; r < 4; r++) {
                        const float p = EXP2(st[mi][kb][r]);
                        st[mi][kb][r] = p;
                        rs += p;
                    }
                l_i[mi] += rs;   // lane-partial; quad-reduced in epilogue
                #pragma unroll
                for (int kb = 0; kb < 4; kb++) {
                    __bf16 pb[4] = {(__bf16)st[mi][kb][0], (__bf16)st[mi][kb][1],
                                    (__bf16)st[mi][kb][2], (__bf16)st[mi][kb][3]};
                    // elem off = kb*16 + quad*4; 16B chunk = kb*2+(quad>>1)
                    const int pc = ((kb * 2 + (quad >> 1)) ^ pkey) * 8 + (quad & 1) * 4;
                    *(uint2*)&Pt[w][mi * 16 + l15][pc] = *(uint2*)pb;
                }
            }

            // ---- O^T += V^T P^T : 64d x 32q x 64k per wave (16 MFMAs) ----
            #pragma unroll
            for (int kh = 0; kh < 2; kh++) {
                bf16x8 pf[2];
                #pragma unroll
                for (int mi = 0; mi < 2; mi++) {
                    // elem off = kh*32 + quad*8; chunk = kh*4+quad
                    const int pc = ((kh * 4 + quad) ^ pkey) * 8;
                    pf[mi] = *(const bf16x8*)&Pt[w][mi * 16 + l15][pc];
                }
                __builtin_amdgcn_s_setprio(1);
                #pragma unroll
                for (int db = 0; db < 4; db++) {
                    const bf16x8 vf = *(const bf16x8*)&Vs[(sub * 2 + kh) * 2048 +
                                          (db * 16 + l15) * 32 + qsw];
                    #pragma unroll
                    for (int mi = 0; mi < 2; mi++)
                        o[mi][db] = MFMA16(vf, pf[mi], o[mi][db]);
                }
                __builtin_amdgcn_s_setprio(0);
            }
        }

        __syncthreads();   // single barrier per 128 keys
    }

    // ---- epilogue: reduce l, normalize, subtract-projection, store ----
    const float xs = xsa[0];
    const int b = bh >> 4, h = bh & (NH - 1);
    const __bf16* Vb = V + (size_t)bh * SEQ * HD;
    #pragma unroll
    for (int mi = 0; mi < 2; mi++) {
        l_i[mi] += __shfl_xor(l_i[mi], 16);
        l_i[mi] += __shfl_xor(l_i[mi], 32);
        const int q = q0 + w * 32 + mi * 16 + l15;   // sequence position
        const float inv = 1.0f / l_i[mi];
        float vv[4][4], on[4][4];
        float dp = 0.0f, nn = 0.0f;
        #pragma unroll
        for (int db = 0; db < 4; db++) {
            __bf16 vb4[4];
            *(uint2*)vb4 = *(const uint2*)&Vb[(size_t)q * HD + db * 16 + quad * 4];
            #pragma unroll
            for (int r = 0; r < 4; r++) {
                const float vf = (float)vb4[r];
                const float of = o[mi][db][r] * inv;
                vv[db][r] = vf;
                on[db][r] = of;
                dp += of * vf;
                nn += vf * vf;
            }
        }
        dp += __shfl_xor(dp, 16); dp += __shfl_xor(dp, 32);
        nn += __shfl_xor(nn, 16); nn += __shfl_xor(nn, 32);
        const float coef = xs * dp / (nn + 1e-8f);
        #pragma unroll
        for (int db = 0; db < 4; db++) {
            __bf16 ob[4];
            #pragma unroll
            for (int r = 0; r < 4; r++)
                ob[r] = (__bf16)(on[db][r] - coef * vv[db][r]);
            *(uint2*)&X2[((size_t)b * SEQ + q) * DM + h * HD + db * 16 + quad * 4] =
                *(uint2*)ob;
        }
    }
}

// ======================================================================
extern "C" void kernel_launch(void* const* d_in, const int* in_sizes, int n_in,
                              void* d_out, int out_size, void* d_ws, size_t ws_size,
                              hipStream_t stream)
{
    (void)in_sizes; (void)n_in; (void)out_size; (void)ws_size;
    const float* x   = (const float*)d_in[0];
    const float* Wq  = (const float*)d_in[1];
    const float* Wk  = (const float*)d_in[2];
    const float* Wv  = (const float*)d_in[3];
    const float* Wo  = (const float*)d_in[4];
    const float* xsa = (const float*)d_in[5];
    float* out = (float*)d_out;

    // workspace layout (bf16 elements): 56 MB total
    __bf16* xb  = (__bf16*)d_ws;        // 4 M
    __bf16* Wb  = xb  + NEL;            // 4 x 1 M (Wq,Wk,Wv,Wo)
    __bf16* Qb  = Wb  + 4 * WEL;        // 4 M  (B,H,S,HD), pre-scaled
    __bf16* Kb  = Qb  + NEL;            // 4 M
    __bf16* Vb  = Kb  + NEL;            // 4 M
    __bf16* Vtb = Vb  + NEL;            // 4 M  (B,H,HD,S)
    __bf16* X2  = Vtb + NEL;            // 4 M  (B,S,DM)

    // all fp32->bf16 conversions in one launch
    cvt_all<<<dim3(8192), 256, 0, stream>>>(x, Wq, Wk, Wv, Wo, xb, Wb);

    // Q/K/V projections (V dual-stored to Vt; Q pre-scaled)
    gemm_nt_mfma<128><<<dim3(DM / 128, MROWS / 128, 3), 256, 0, stream>>>(
        xb, Wb, Qb, Vtb, 1);

    // attention + fused subtract-projection -> X2 (1D XCD-pinned grid,
    // 128q / 4-wave blocks, KVBLK=128)
    attn_mfma<<<dim3((SEQ / 128) * BATCH * NH), 256, 0, stream>>>(
        Qb, Kb, Vtb, Vb, xsa, X2);

    // output projection (BN=64 -> 512 blocks for occupancy), fp32 out
    gemm_nt_mfma<64><<<dim3(DM / 64, MROWS / 128, 1), 256, 0, stream>>>(
        X2, Wb + 3 * WEL, out, nullptr, 0);
}

// Round 6
// 183.862 us; speedup vs baseline: 1.1146x; 1.0444x over previous
//
#include <hip/hip_runtime.h>
#include <math.h>

// Problem constants
#define BATCH 2
#define SEQ   2048
#define NH    16
#define HD    64
#define DM    1024
#define MROWS (BATCH * SEQ)                  // 4096
#define NEL   ((size_t)MROWS * DM)           // 4 M elements (activation buffer)
#define WEL   ((size_t)DM * DM)              // 1 M elements (weight buffer)
// softmax scale folded into Q at projection: 1/sqrt(64) * log2(e)
#define SM_SCALE_LOG2E 0.18033688011112042f

typedef __bf16 bf16x8 __attribute__((ext_vector_type(8)));
typedef float  f32x4  __attribute__((ext_vector_type(4)));

#define MFMA16(a, b, c) __builtin_amdgcn_mfma_f32_16x16x32_bf16((a), (b), (c), 0, 0, 0)
#define EXP2(x) __builtin_amdgcn_exp2f(x)

// async global->LDS, 16B per lane; LDS dest = wave-uniform base + lane*16
#define GLDS16(g, s) __builtin_amdgcn_global_load_lds( \
    (const __attribute__((address_space(1))) void*)(g), \
    (__attribute__((address_space(3))) void*)(s), 16, 0, 0)

// ----------------------------------------------------------------------
// LDS swizzles (verified R2/R3): K/V/Q tiles [row][32] use chunk' =
// chunk ^ ((row>>1)&3) staged via pre-swizzled GLOBAL source column;
// Pt [row][64] uses 16B-chunk ^ (row&7) on write and read.
// XCD pinning (verified R3): bh = id&31 -> id%8 == bh%8; FETCH 74->16 MB.
// R4 lesson: 2-wave blocks double K/V streaming -> regression; 4-wave/128q.
// R5 win: KVBLK=128 + epilogue l_i reduce -> attn 58->53us.
// R6: Vt was written as a 2B-granular stride-4KB scatter in the z==2 GEMM
// epilogue (64 lanes -> 16 strips/instr, <=25% line use, 16K scatter
// instrs/block). Replaced with LDS-transpose epilogue: acc -> T[col][s]
// (8B writes, chunk^col swizzle), barrier, coalesced uint4 Vt stores.
// ----------------------------------------------------------------------

// ======================================================================
// fp32 -> bf16 convert, single launch: blocks [0,4096) convert x,
// blocks [4096,8192) convert the 4 weight matrices.
// ======================================================================
__global__ __launch_bounds__(256) void cvt_all(
    const float* __restrict__ x,
    const float* __restrict__ w0, const float* __restrict__ w1,
    const float* __restrict__ w2, const float* __restrict__ w3,
    __bf16* __restrict__ xb, __bf16* __restrict__ wb)
{
    const int bid = blockIdx.x;
    const float* src;
    __bf16* dst;
    size_t base;
    if (bid < 4096) {
        src = x; dst = xb; base = (size_t)bid * 1024;
    } else {
        const int r = bid - 4096;
        const int z = r >> 10;
        src = (z == 0) ? w0 : (z == 1) ? w1 : (z == 2) ? w2 : w3;
        dst = wb + (size_t)z * WEL;
        base = (size_t)(r & 1023) * 1024;
    }
    const size_t i = base + (size_t)threadIdx.x * 4;
    const float4 f = *(const float4*)&src[i];
    __bf16 b[4] = {(__bf16)f.x, (__bf16)f.y, (__bf16)f.z, (__bf16)f.w};
    *(ushort4*)&dst[i] = *(ushort4*)b;
}

// ======================================================================
// NT bf16 MFMA GEMM, single-barrier double-buffered K-loop.
// C[m,n] = sum_k A[m,k]*W[n,k]. Tile 128 x BN, BK=32, 4 waves.
// LDS k-chunk XOR-swizzled -> conflict-free b128 fragment reads.
// mode 1 (BN=128): z selects weight+output slab; bf16 store permuted to
//   (B,H,S,HD); z==0 (Q) pre-scaled; z==2 (V) additionally transposed
//   through LDS and stored coalesced to Vt (B,H,HD,S).
// mode 0: fp32 row-major M x DM store.
// ======================================================================
template<int BN>
__global__ __launch_bounds__(256) void gemm_nt_mfma(
    const __bf16* __restrict__ A, const __bf16* __restrict__ W0,
    void* __restrict__ C0, __bf16* __restrict__ Vt, int mode)
{
    constexpr int NI  = BN / 32;         // 16-col groups per wave
    constexpr int NIT = DM / 32;         // 32 K-iterations
    // flat LDS: A dbuf (2x4096) + B dbuf (2x BN*32); for BN=128 the whole
    // 16384-elem pool is reused as the 128x128 transpose buffer T.
    __shared__ __bf16 lds[2 * 128 * 32 + 2 * BN * 32];
    #define AST(buf) (lds + (buf) * 4096)
    #define BST(buf) (lds + 8192 + (buf) * (BN * 32))

    const int t = threadIdx.x;
    const int w = t >> 6, l = t & 63;
    const int quad = l >> 4, l15 = l & 15;
    const int z = blockIdx.z;
    const int m0 = blockIdx.y * 128, n0 = blockIdx.x * BN;
    const int wm = (w >> 1) * 64, wn = (w & 1) * (BN / 2);

    const __bf16* Wp = W0 + (size_t)z * WEL;

    const int lrow = l >> 2;           // staging: lane row within 16-row instr
    // staging k-offset: pre-swizzled global source column (rule #21)
    const int lkof = ((l & 3) ^ ((lrow >> 1) & 3)) * 8;
    // read-side swizzled k-chunk (row bits 1..2 == l15 bits 1..2)
    const int qsw = (quad ^ ((l15 >> 1) & 3)) * 8;

    const __bf16* Ag = A + (size_t)(m0 + w * 32 + lrow) * DM + lkof;
    const int aoff = (w * 32) * 32;    // wave-uniform LDS offset (A)
    // B staging: BN=128 -> 2 instrs/wave (rows w*32); BN=64 -> 1 (rows w*16)
    const int brow = (BN == 128) ? (w * 32) : (w * 16);
    const __bf16* Bg = Wp + (size_t)(n0 + brow + lrow) * DM + lkof;
    const int boff = brow * 32;

    f32x4 acc[4][NI];
    #pragma unroll
    for (int i = 0; i < 4; i++)
        #pragma unroll
        for (int j = 0; j < NI; j++) acc[i][j] = (f32x4)0.0f;

    // prologue: tile 0 -> buf 0
    GLDS16(Ag,           AST(0) + aoff);
    GLDS16(Ag + 16 * DM, AST(0) + aoff + 512);
    GLDS16(Bg,           BST(0) + boff);
    if (BN == 128) GLDS16(Bg + 16 * DM, BST(0) + boff + 512);
    __syncthreads();

    for (int i = 0; i < NIT; i++) {
        const int cur = i & 1, nxt = cur ^ 1;
        if (i + 1 < NIT) {
            const int k0 = (i + 1) * 32;
            GLDS16(Ag + k0,           AST(nxt) + aoff);
            GLDS16(Ag + k0 + 16 * DM, AST(nxt) + aoff + 512);
            GLDS16(Bg + k0,           BST(nxt) + boff);
            if (BN == 128) GLDS16(Bg + k0 + 16 * DM, BST(nxt) + boff + 512);
        }

        bf16x8 af[4], bfr[NI];
        #pragma unroll
        for (int mi = 0; mi < 4; mi++)
            af[mi] = *(const bf16x8*)&AST(cur)[(wm + mi * 16 + l15) * 32 + qsw];
        #pragma unroll
        for (int ni = 0; ni < NI; ni++)
            bfr[ni] = *(const bf16x8*)&BST(cur)[(wn + ni * 16 + l15) * 32 + qsw];
        __builtin_amdgcn_s_setprio(1);
        #pragma unroll
        for (int mi = 0; mi < 4; mi++)
            #pragma unroll
            for (int ni = 0; ni < NI; ni++)
                acc[mi][ni] = MFMA16(af[mi], bfr[ni], acc[mi][ni]);
        __builtin_amdgcn_s_setprio(0);

        __syncthreads();   // single barrier: drains prefetch, fences buffers
    }

    if (mode) {
        const float sc = (z == 0) ? SM_SCALE_LOG2E : 1.0f;
        __bf16* C = (__bf16*)C0 + (size_t)z * NEL;
        #pragma unroll
        for (int mi = 0; mi < 4; mi++)
            #pragma unroll
            for (int ni = 0; ni < NI; ni++)
                #pragma unroll
                for (int r = 0; r < 4; r++) {
                    const int row = m0 + wm + mi * 16 + quad * 4 + r;
                    const int col = n0 + wn + ni * 16 + l15;
                    const int b = row >> 11, s = row & (SEQ - 1);
                    const int h = col >> 6,  d = col & (HD - 1);
                    const __bf16 val = (__bf16)(acc[mi][ni][r] * sc);
                    C[((size_t)(b * NH + h) * SEQ + s) * HD + d] = val;
                }

        if constexpr (BN == 128) {
            if (z == 2) {
                // ---- Vt via LDS transpose: T[col 128][s 128], 16B-chunk
                // swizzle sc^(col&7). acc r-values are s-consecutive ->
                // one 8B packed write per (mi,ni).
                __bf16* T = lds;   // staging buffers dead after final barrier
                #pragma unroll
                for (int mi = 0; mi < 4; mi++)
                    #pragma unroll
                    for (int ni = 0; ni < 4; ni++) {
                        const int cl = wn + ni * 16 + l15;
                        const int s0 = wm + mi * 16 + quad * 4;
                        __bf16 pb[4] = {(__bf16)acc[mi][ni][0], (__bf16)acc[mi][ni][1],
                                        (__bf16)acc[mi][ni][2], (__bf16)acc[mi][ni][3]};
                        const int scn = s0 >> 3;          // 16B chunk along s
                        const int sub = (s0 >> 2) & 1;    // 8B half
                        *(uint2*)&T[cl * 128 + ((scn ^ (cl & 7)) * 8) + sub * 4] =
                            *(uint2*)pb;
                    }
                __syncthreads();
                // read back coalesced: per instr, 8 cols x 8 consecutive
                // 16B chunks (128B runs) -> uint4 stores to Vt
                const int b = m0 >> 11;
                const int sbase = m0 & (SEQ - 1);
                #pragma unroll
                for (int u = 0; u < 8; u++) {
                    const int cl = ((u >> 1) * 32) + (t >> 3);
                    const int ci = (u & 1) * 8 + (t & 7);
                    const int hh = (n0 + cl) >> 6, dd = (n0 + cl) & (HD - 1);
                    const uint4 v = *(const uint4*)&T[cl * 128 + ((ci ^ (cl & 7)) * 8)];
                    *(uint4*)&Vt[((size_t)(b * NH + hh) * HD + dd) * SEQ +
                                 sbase + ci * 8] = v;
                }
            }
        }
    } else {
        float* C = (float*)C0;
        #pragma unroll
        for (int mi = 0; mi < 4; mi++)
            #pragma unroll
            for (int ni = 0; ni < NI; ni++)
                #pragma unroll
                for (int r = 0; r < 4; r++) {
                    const int row = m0 + wm + mi * 16 + quad * 4 + r;
                    const int col = n0 + wn + ni * 16 + l15;
                    C[(size_t)row * DM + col] = acc[mi][ni][r];
                }
    }
    #undef AST
    #undef BST
}

// ======================================================================
// Flash attention v8 (unchanged from R5): 4-wave/128q, KVBLK=128,
// deferred l_i, XCD-pinned 1D grid, swizzled K/V/Q + Pt, setprio.
// LDS: KV dbuf 2 x 32 KB + Pt 16 KB = 80 KB -> 2 blocks/CU (grid 512).
// ======================================================================
__global__ __launch_bounds__(256, 2) void attn_mfma(
    const __bf16* __restrict__ Q, const __bf16* __restrict__ K,
    const __bf16* __restrict__ Vt, const __bf16* __restrict__ V,
    const float* __restrict__ xsa, __bf16* __restrict__ X2)
{
    // KV[buf][0] = K region [h][key128][32]  (h*4096 + key*32 + j)
    // KV[buf][1] = V region [kg][dim64][32]  (kg*2048 + dim*32 + j), kg=key/32
    __shared__ __bf16 KV[2][2][8192];
    __shared__ __bf16 Pt[4][32][64];   // per-wave P [q][key64], XOR-swizzled

    const int t = threadIdx.x;
    const int w = t >> 6, l = t & 63;
    const int quad = l >> 4, l15 = l & 15;
    // XCD-pinned decomposition: id%8 == bh%8 -> one XCD per (b,h)
    const int bh = blockIdx.x & 31;
    const int q0 = (blockIdx.x >> 5) * 128;

    const __bf16* Qb  = Q  + (size_t)bh * SEQ * HD;
    const __bf16* Kb  = K  + (size_t)bh * SEQ * HD;
    const __bf16* Vtb = Vt + (size_t)bh * HD * SEQ;

    const int lrow = l >> 2;
    // staging k-offset: pre-swizzled global source column (rule #21)
    const int lkof = ((l & 3) ^ ((lrow >> 1) & 3)) * 8;
    // read-side swizzled k-chunk
    const int qsw = (quad ^ ((l15 >> 1) & 3)) * 8;
    // Pt swizzle key: row & 7 == l15 & 7 for all Pt accesses
    const int pkey = l15 & 7;

    // ---- prologue: stage Q into KV[1][0] (16 KB overlay) + K0/V0 -> KV[0]
    __bf16* Qst = &KV[1][0][0];   // flat [h][q128][32]: h*4096 + q*32 + j
    #pragma unroll
    for (int h = 0; h < 2; h++)
        #pragma unroll
        for (int qq = 0; qq < 2; qq++)
            GLDS16(Qb + (size_t)(q0 + w * 32 + qq * 16 + lrow) * HD + h * 32 + lkof,
                   Qst + h * 4096 + (w * 32 + qq * 16) * 32);
    #pragma unroll
    for (int h = 0; h < 2; h++)
        #pragma unroll
        for (int qq = 0; qq < 2; qq++)
            GLDS16(Kb + (size_t)(w * 32 + qq * 16 + lrow) * HD + h * 32 + lkof,
                   &KV[0][0][h * 4096 + (w * 32 + qq * 16) * 32]);
    #pragma unroll
    for (int kg = 0; kg < 4; kg++)
        GLDS16(Vtb + (size_t)(w * 16 + lrow) * SEQ + kg * 32 + lkof,
               &KV[0][1][kg * 2048 + (w * 16) * 32]);
    __syncthreads();   // all prologue staging visible

    // ---- hoist Q fragments to registers (loop-invariant) ----
    bf16x8 qf[2][2];   // [half][mi]
    #pragma unroll
    for (int h = 0; h < 2; h++)
        #pragma unroll
        for (int mi = 0; mi < 2; mi++)
            qf[h][mi] = *(const bf16x8*)&Qst[h * 4096 +
                          (w * 32 + mi * 16 + l15) * 32 + qsw];
    __syncthreads();   // Q reads done before kt=0 prefetch overwrites KV[1]

    float l_i[2] = {0.0f, 0.0f};   // per-lane partials; reduced in epilogue
    f32x4 o[2][4];
    #pragma unroll
    for (int mi = 0; mi < 2; mi++)
        #pragma unroll
        for (int db = 0; db < 4; db++) o[mi][db] = (f32x4)0.0f;

    constexpr int NT = SEQ / 128;   // 16 key tiles of 128
    for (int kt = 0; kt < NT; kt++) {
        const int cur = kt & 1, nxt = cur ^ 1;
        if (kt + 1 < NT) {
            const int k0n = (kt + 1) * 128;
            #pragma unroll
            for (int h = 0; h < 2; h++)
                #pragma unroll
                for (int qq = 0; qq < 2; qq++)
                    GLDS16(Kb + (size_t)(k0n + w * 32 + qq * 16 + lrow) * HD + h * 32 + lkof,
                           &KV[nxt][0][h * 4096 + (w * 32 + qq * 16) * 32]);
            #pragma unroll
            for (int kg = 0; kg < 4; kg++)
                GLDS16(Vtb + (size_t)(w * 16 + lrow) * SEQ + k0n + kg * 32 + lkof,
                       &KV[nxt][1][kg * 2048 + (w * 16) * 32]);
        }
        const __bf16* Ks = &KV[cur][0][0];
        const __bf16* Vs = &KV[cur][1][0];

        // two 64-key sub-phases; per-wave Pt reused with no block sync
        #pragma unroll
        for (int sub = 0; sub < 2; sub++) {
            // ---- S^T = K Q^T : 64k x 32q x 64d per wave (16 MFMAs) ----
            f32x4 st[2][4];
            #pragma unroll
            for (int mi = 0; mi < 2; mi++)
                #pragma unroll
                for (int kb = 0; kb < 4; kb++) st[mi][kb] = (f32x4)0.0f;
            __builtin_amdgcn_s_setprio(1);
            #pragma unroll
            for (int h = 0; h < 2; h++)
                #pragma unroll
                for (int kb = 0; kb < 4; kb++) {
                    const bf16x8 kf = *(const bf16x8*)&Ks[h * 4096 +
                                          (sub * 64 + kb * 16 + l15) * 32 + qsw];
                    #pragma unroll
                    for (int mi = 0; mi < 2; mi++)
                        st[mi][kb] = MFMA16(kf, qf[h][mi], st[mi][kb]);
                }
            __builtin_amdgcn_s_setprio(0);

            // ---- fixed-shift softmax: p = exp2(s), per-lane l partial ----
            #pragma unroll
            for (int mi = 0; mi < 2; mi++) {
                float rs = 0.0f;
                #pragma unroll
                for (int kb = 0; kb < 4; kb++)
                    #pragma unroll
                    for (int r = 0; r < 4; r++) {
                        const float p = EXP2(st[mi][kb][r]);
                        st[mi][kb][r] = p;
                        rs += p;
                    }
                l_i[mi] += rs;   // lane-partial; quad-reduced in epilogue
                #pragma unroll
                for (int kb = 0; kb < 4; kb++) {
                    __bf16 pb[4] = {(__bf16)st[mi][kb][0], (__bf16)st[mi][kb][1],
                                    (__bf16)st[mi][kb][2], (__bf16)st[mi][kb][3]};
                    // elem off = kb*16 + quad*4; 16B chunk = kb*2+(quad>>1)
                    const int pc = ((kb * 2 + (quad >> 1)) ^ pkey) * 8 + (quad & 1) * 4;
                    *(uint2*)&Pt[w][mi * 16 + l15][pc] = *(uint2*)pb;
                }
            }

            // ---- O^T += V^T P^T : 64d x 32q x 64k per wave (16 MFMAs) ----
            #pragma unroll
            for (int kh = 0; kh < 2; kh++) {
                bf16x8 pf[2];
                #pragma unroll
                for (int mi = 0; mi < 2; mi++) {
                    // elem off = kh*32 + quad*8; chunk = kh*4+quad
                    const int pc = ((kh * 4 + quad) ^ pkey) * 8;
                    pf[mi] = *(const bf16x8*)&Pt[w][mi * 16 + l15][pc];
                }
                __builtin_amdgcn_s_setprio(1);
                #pragma unroll
                for (int db = 0; db < 4; db++) {
                    const bf16x8 vf = *(const bf16x8*)&Vs[(sub * 2 + kh) * 2048 +
                                          (db * 16 + l15) * 32 + qsw];
                    #pragma unroll
                    for (int mi = 0; mi < 2; mi++)
                        o[mi][db] = MFMA16(vf, pf[mi], o[mi][db]);
                }
                __builtin_amdgcn_s_setprio(0);
            }
        }

        __syncthreads();   // single barrier per 128 keys
    }

    // ---- epilogue: reduce l, normalize, subtract-projection, store ----
    const float xs = xsa[0];
    const int b = bh >> 4, h = bh & (NH - 1);
    const __bf16* Vb = V + (size_t)bh * SEQ * HD;
    #pragma unroll
    for (int mi = 0; mi < 2; mi++) {
        l_i[mi] += __shfl_xor(l_i[mi], 16);
        l_i[mi] += __shfl_xor(l_i[mi], 32);
        const int q = q0 + w * 32 + mi * 16 + l15;   // sequence position
        const float inv = 1.0f / l_i[mi];
        float vv[4][4], on[4][4];
        float dp = 0.0f, nn = 0.0f;
        #pragma unroll
        for (int db = 0; db < 4; db++) {
            __bf16 vb4[4];
            *(uint2*)vb4 = *(const uint2*)&Vb[(size_t)q * HD + db * 16 + quad * 4];
            #pragma unroll
            for (int r = 0; r < 4; r++) {
                const float vf = (float)vb4[r];
                const float of = o[mi][db][r] * inv;
                vv[db][r] = vf;
                on[db][r] = of;
                dp += of * vf;
                nn += vf * vf;
            }
        }
        dp += __shfl_xor(dp, 16); dp += __shfl_xor(dp, 32);
        nn += __shfl_xor(nn, 16); nn += __shfl_xor(nn, 32);
        const float coef = xs * dp / (nn + 1e-8f);
        #pragma unroll
        for (int db = 0; db < 4; db++) {
            __bf16 ob[4];
            #pragma unroll
            for (int r = 0; r < 4; r++)
                ob[r] = (__bf16)(on[db][r] - coef * vv[db][r]);
            *(uint2*)&X2[((size_t)b * SEQ + q) * DM + h * HD + db * 16 + quad * 4] =
                *(uint2*)ob;
        }
    }
}

// ======================================================================
extern "C" void kernel_launch(void* const* d_in, const int* in_sizes, int n_in,
                              void* d_out, int out_size, void* d_ws, size_t ws_size,
                              hipStream_t stream)
{
    (void)in_sizes; (void)n_in; (void)out_size; (void)ws_size;
    const float* x   = (const float*)d_in[0];
    const float* Wq  = (const float*)d_in[1];
    const float* Wk  = (const float*)d_in[2];
    const float* Wv  = (const float*)d_in[3];
    const float* Wo  = (const float*)d_in[4];
    const float* xsa = (const float*)d_in[5];
    float* out = (float*)d_out;

    // workspace layout (bf16 elements): 56 MB total
    __bf16* xb  = (__bf16*)d_ws;        // 4 M
    __bf16* Wb  = xb  + NEL;            // 4 x 1 M (Wq,Wk,Wv,Wo)
    __bf16* Qb  = Wb  + 4 * WEL;        // 4 M  (B,H,S,HD), pre-scaled
    __bf16* Kb  = Qb  + NEL;            // 4 M
    __bf16* Vb  = Kb  + NEL;            // 4 M
    __bf16* Vtb = Vb  + NEL;            // 4 M  (B,H,HD,S)
    __bf16* X2  = Vtb + NEL;            // 4 M  (B,S,DM)

    // all fp32->bf16 conversions in one launch
    cvt_all<<<dim3(8192), 256, 0, stream>>>(x, Wq, Wk, Wv, Wo, xb, Wb);

    // Q/K/V projections (V transposed to Vt via LDS; Q pre-scaled)
    gemm_nt_mfma<128><<<dim3(DM / 128, MROWS / 128, 3), 256, 0, stream>>>(
        xb, Wb, Qb, Vtb, 1);

    // attention + fused subtract-projection -> X2 (1D XCD-pinned grid,
    // 128q / 4-wave blocks, KVBLK=128)
    attn_mfma<<<dim3((SEQ / 128) * BATCH * NH), 256, 0, stream>>>(
        Qb, Kb, Vtb, Vb, xsa, X2);

    // output projection (BN=64 -> 512 blocks for occupancy), fp32 out
    gemm_nt_mfma<64><<<dim3(DM / 64, MROWS / 128, 1), 256, 0, stream>>>(
        X2, Wb + 3 * WEL, out, nullptr, 0);
}

// Round 7
// 178.662 us; speedup vs baseline: 1.1471x; 1.0291x over previous
//
#include <hip/hip_runtime.h>
#include <math.h>

// Problem constants
#define BATCH 2
#define SEQ   2048
#define NH    16
#define HD    64
#define DM    1024
#define MROWS (BATCH * SEQ)                  // 4096
#define NEL   ((size_t)MROWS * DM)           // 4 M elements (activation buffer)
#define WEL   ((size_t)DM * DM)              // 1 M elements (weight buffer)
// softmax scale folded into Q at projection: 1/sqrt(64) * log2(e)
#define SM_SCALE_LOG2E 0.18033688011112042f

typedef __bf16 bf16x8 __attribute__((ext_vector_type(8)));
typedef float  f32x4  __attribute__((ext_vector_type(4)));

#define MFMA16(a, b, c) __builtin_amdgcn_mfma_f32_16x16x32_bf16((a), (b), (c), 0, 0, 0)
#define EXP2(x) __builtin_amdgcn_exp2f(x)

// async global->LDS, 16B per lane; LDS dest = wave-uniform base + lane*16
#define GLDS16(g, s) __builtin_amdgcn_global_load_lds( \
    (const __attribute__((address_space(1))) void*)(g), \
    (__attribute__((address_space(3))) void*)(s), 16, 0, 0)

// ----------------------------------------------------------------------
// LDS swizzles (verified R2/R3): K/V/Q tiles [row][32] use chunk' =
// chunk ^ ((row>>1)&3) staged via pre-swizzled GLOBAL source column;
// Pt [row][64] uses 16B-chunk ^ (row&7) on write and read.
// XCD pinning (verified R3 on attn: FETCH 74->16 MB): id%8 selects XCD.
// R5 win: KVBLK=128 + epilogue l_i reduce -> attn 58->53us.
// R6 win: Vt scatter -> LDS-transpose epilogue, total 192->184us.
// R7: apply XCD pinning to BOTH GEMMs (same mechanism as attn's R3 win):
// XCD k owns y-chunk {4k..4k+3} x all x-blocks, same A-chunk across
// z-slabs. Per-XCD/z working set: A 1MB + W 2MB = 3MB < 4MB L2.
// ----------------------------------------------------------------------

// ======================================================================
// fp32 -> bf16 convert, single launch: blocks [0,4096) convert x,
// blocks [4096,8192) convert the 4 weight matrices.
// ======================================================================
__global__ __launch_bounds__(256) void cvt_all(
    const float* __restrict__ x,
    const float* __restrict__ w0, const float* __restrict__ w1,
    const float* __restrict__ w2, const float* __restrict__ w3,
    __bf16* __restrict__ xb, __bf16* __restrict__ wb)
{
    const int bid = blockIdx.x;
    const float* src;
    __bf16* dst;
    size_t base;
    if (bid < 4096) {
        src = x; dst = xb; base = (size_t)bid * 1024;
    } else {
        const int r = bid - 4096;
        const int z = r >> 10;
        src = (z == 0) ? w0 : (z == 1) ? w1 : (z == 2) ? w2 : w3;
        dst = wb + (size_t)z * WEL;
        base = (size_t)(r & 1023) * 1024;
    }
    const size_t i = base + (size_t)threadIdx.x * 4;
    const float4 f = *(const float4*)&src[i];
    __bf16 b[4] = {(__bf16)f.x, (__bf16)f.y, (__bf16)f.z, (__bf16)f.w};
    *(ushort4*)&dst[i] = *(ushort4*)b;
}

// ======================================================================
// NT bf16 MFMA GEMM, single-barrier double-buffered K-loop.
// C[m,n] = sum_k A[m,k]*W[n,k]. Tile 128 x BN, BK=32, 4 waves.
// 1D XCD-pinned grid: id -> (xcd=id&7, x, z, yq), y = xcd*4+yq.
//   Each XCD keeps a 1MB A-chunk resident and streams one 2MB W slab
//   at a time (3MB < 4MB per-XCD L2).
// LDS k-chunk XOR-swizzled -> conflict-free b128 fragment reads.
// NZ=3 (BN=128): z selects weight+output slab; bf16 store permuted to
//   (B,H,S,HD); z==0 (Q) pre-scaled; z==2 (V) additionally transposed
//   through LDS and stored coalesced to Vt (B,H,HD,S).
// NZ=1 (BN=64): fp32 row-major M x DM store (mode 0).
// ======================================================================
template<int BN, int NZ>
__global__ __launch_bounds__(256) void gemm_nt_mfma(
    const __bf16* __restrict__ A, const __bf16* __restrict__ W0,
    void* __restrict__ C0, __bf16* __restrict__ Vt, int mode)
{
    constexpr int NI  = BN / 32;         // 16-col groups per wave
    constexpr int NIT = DM / 32;         // 32 K-iterations
    constexpr int NX  = DM / BN;         // 8 (BN=128) or 16 (BN=64)
    constexpr int LNX = (BN == 128) ? 3 : 4;
    // flat LDS: A dbuf (2x4096) + B dbuf (2x BN*32); for BN=128 the whole
    // 16384-elem pool is reused as the 128x128 transpose buffer T.
    __shared__ __bf16 lds[2 * 128 * 32 + 2 * BN * 32];
    #define AST(buf) (lds + (buf) * 4096)
    #define BST(buf) (lds + 8192 + (buf) * (BN * 32))

    const int t = threadIdx.x;
    const int w = t >> 6, l = t & 63;
    const int quad = l >> 4, l15 = l & 15;

    // XCD-pinned decomposition (bijective: 8 * NX * 4*NZ blocks)
    const int id  = blockIdx.x;
    const int xcd = id & 7;
    const int g   = id >> 3;
    const int x   = g & (NX - 1);
    const int r0  = g >> LNX;            // [0, 4*NZ)
    const int z   = r0 >> 2;
    const int yq  = r0 & 3;
    const int y   = xcd * 4 + yq;
    const int m0 = y * 128, n0 = x * BN;
    const int wm = (w >> 1) * 64, wn = (w & 1) * (BN / 2);

    const __bf16* Wp = W0 + (size_t)z * WEL;

    const int lrow = l >> 2;           // staging: lane row within 16-row instr
    // staging k-offset: pre-swizzled global source column (rule #21)
    const int lkof = ((l & 3) ^ ((lrow >> 1) & 3)) * 8;
    // read-side swizzled k-chunk (row bits 1..2 == l15 bits 1..2)
    const int qsw = (quad ^ ((l15 >> 1) & 3)) * 8;

    const __bf16* Ag = A + (size_t)(m0 + w * 32 + lrow) * DM + lkof;
    const int aoff = (w * 32) * 32;    // wave-uniform LDS offset (A)
    // B staging: BN=128 -> 2 instrs/wave (rows w*32); BN=64 -> 1 (rows w*16)
    const int brow = (BN == 128) ? (w * 32) : (w * 16);
    const __bf16* Bg = Wp + (size_t)(n0 + brow + lrow) * DM + lkof;
    const int boff = brow * 32;

    f32x4 acc[4][NI];
    #pragma unroll
    for (int i = 0; i < 4; i++)
        #pragma unroll
        for (int j = 0; j < NI; j++) acc[i][j] = (f32x4)0.0f;

    // prologue: tile 0 -> buf 0
    GLDS16(Ag,           AST(0) + aoff);
    GLDS16(Ag + 16 * DM, AST(0) + aoff + 512);
    GLDS16(Bg,           BST(0) + boff);
    if (BN == 128) GLDS16(Bg + 16 * DM, BST(0) + boff + 512);
    __syncthreads();

    for (int i = 0; i < NIT; i++) {
        const int cur = i & 1, nxt = cur ^ 1;
        if (i + 1 < NIT) {
            const int k0 = (i + 1) * 32;
            GLDS16(Ag + k0,           AST(nxt) + aoff);
            GLDS16(Ag + k0 + 16 * DM, AST(nxt) + aoff + 512);
            GLDS16(Bg + k0,           BST(nxt) + boff);
            if (BN == 128) GLDS16(Bg + k0 + 16 * DM, BST(nxt) + boff + 512);
        }

        bf16x8 af[4], bfr[NI];
        #pragma unroll
        for (int mi = 0; mi < 4; mi++)
            af[mi] = *(const bf16x8*)&AST(cur)[(wm + mi * 16 + l15) * 32 + qsw];
        #pragma unroll
        for (int ni = 0; ni < NI; ni++)
            bfr[ni] = *(const bf16x8*)&BST(cur)[(wn + ni * 16 + l15) * 32 + qsw];
        __builtin_amdgcn_s_setprio(1);
        #pragma unroll
        for (int mi = 0; mi < 4; mi++)
            #pragma unroll
            for (int ni = 0; ni < NI; ni++)
                acc[mi][ni] = MFMA16(af[mi], bfr[ni], acc[mi][ni]);
        __builtin_amdgcn_s_setprio(0);

        __syncthreads();   // single barrier: drains prefetch, fences buffers
    }

    if (mode) {
        const float sc = (z == 0) ? SM_SCALE_LOG2E : 1.0f;
        __bf16* C = (__bf16*)C0 + (size_t)z * NEL;
        #pragma unroll
        for (int mi = 0; mi < 4; mi++)
            #pragma unroll
            for (int ni = 0; ni < NI; ni++)
                #pragma unroll
                for (int r = 0; r < 4; r++) {
                    const int row = m0 + wm + mi * 16 + quad * 4 + r;
                    const int col = n0 + wn + ni * 16 + l15;
                    const int b = row >> 11, s = row & (SEQ - 1);
                    const int h = col >> 6,  d = col & (HD - 1);
                    const __bf16 val = (__bf16)(acc[mi][ni][r] * sc);
                    C[((size_t)(b * NH + h) * SEQ + s) * HD + d] = val;
                }

        if constexpr (BN == 128) {
            if (z == 2) {
                // ---- Vt via LDS transpose: T[col 128][s 128], 16B-chunk
                // swizzle sc^(col&7). acc r-values are s-consecutive ->
                // one 8B packed write per (mi,ni).
                __bf16* T = lds;   // staging buffers dead after final barrier
                #pragma unroll
                for (int mi = 0; mi < 4; mi++)
                    #pragma unroll
                    for (int ni = 0; ni < 4; ni++) {
                        const int cl = wn + ni * 16 + l15;
                        const int s0 = wm + mi * 16 + quad * 4;
                        __bf16 pb[4] = {(__bf16)acc[mi][ni][0], (__bf16)acc[mi][ni][1],
                                        (__bf16)acc[mi][ni][2], (__bf16)acc[mi][ni][3]};
                        const int scn = s0 >> 3;          // 16B chunk along s
                        const int sub = (s0 >> 2) & 1;    // 8B half
                        *(uint2*)&T[cl * 128 + ((scn ^ (cl & 7)) * 8) + sub * 4] =
                            *(uint2*)pb;
                    }
                __syncthreads();
                // read back coalesced: per instr, 8 cols x 8 consecutive
                // 16B chunks (128B runs) -> uint4 stores to Vt
                const int b = m0 >> 11;
                const int sbase = m0 & (SEQ - 1);
                #pragma unroll
                for (int u = 0; u < 8; u++) {
                    const int cl = ((u >> 1) * 32) + (t >> 3);
                    const int ci = (u & 1) * 8 + (t & 7);
                    const int hh = (n0 + cl) >> 6, dd = (n0 + cl) & (HD - 1);
                    const uint4 v = *(const uint4*)&T[cl * 128 + ((ci ^ (cl & 7)) * 8)];
                    *(uint4*)&Vt[((size_t)(b * NH + hh) * HD + dd) * SEQ +
                                 sbase + ci * 8] = v;
                }
            }
        }
    } else {
        float* C = (float*)C0;
        #pragma unroll
        for (int mi = 0; mi < 4; mi++)
            #pragma unroll
            for (int ni = 0; ni < NI; ni++)
                #pragma unroll
                for (int r = 0; r < 4; r++) {
                    const int row = m0 + wm + mi * 16 + quad * 4 + r;
                    const int col = n0 + wn + ni * 16 + l15;
                    C[(size_t)row * DM + col] = acc[mi][ni][r];
                }
    }
    #undef AST
    #undef BST
}

// ======================================================================
// Flash attention v8 (unchanged from R5): 4-wave/128q, KVBLK=128,
// deferred l_i, XCD-pinned 1D grid, swizzled K/V/Q + Pt, setprio.
// LDS: KV dbuf 2 x 32 KB + Pt 16 KB = 80 KB -> 2 blocks/CU (grid 512).
// ======================================================================
__global__ __launch_bounds__(256, 2) void attn_mfma(
    const __bf16* __restrict__ Q, const __bf16* __restrict__ K,
    const __bf16* __restrict__ Vt, const __bf16* __restrict__ V,
    const float* __restrict__ xsa, __bf16* __restrict__ X2)
{
    // KV[buf][0] = K region [h][key128][32]  (h*4096 + key*32 + j)
    // KV[buf][1] = V region [kg][dim64][32]  (kg*2048 + dim*32 + j), kg=key/32
    __shared__ __bf16 KV[2][2][8192];
    __shared__ __bf16 Pt[4][32][64];   // per-wave P [q][key64], XOR-swizzled

    const int t = threadIdx.x;
    const int w = t >> 6, l = t & 63;
    const int quad = l >> 4, l15 = l & 15;
    // XCD-pinned decomposition: id%8 == bh%8 -> one XCD per (b,h)
    const int bh = blockIdx.x & 31;
    const int q0 = (blockIdx.x >> 5) * 128;

    const __bf16* Qb  = Q  + (size_t)bh * SEQ * HD;
    const __bf16* Kb  = K  + (size_t)bh * SEQ * HD;
    const __bf16* Vtb = Vt + (size_t)bh * HD * SEQ;

    const int lrow = l >> 2;
    // staging k-offset: pre-swizzled global source column (rule #21)
    const int lkof = ((l & 3) ^ ((lrow >> 1) & 3)) * 8;
    // read-side swizzled k-chunk
    const int qsw = (quad ^ ((l15 >> 1) & 3)) * 8;
    // Pt swizzle key: row & 7 == l15 & 7 for all Pt accesses
    const int pkey = l15 & 7;

    // ---- prologue: stage Q into KV[1][0] (16 KB overlay) + K0/V0 -> KV[0]
    __bf16* Qst = &KV[1][0][0];   // flat [h][q128][32]: h*4096 + q*32 + j
    #pragma unroll
    for (int h = 0; h < 2; h++)
        #pragma unroll
        for (int qq = 0; qq < 2; qq++)
            GLDS16(Qb + (size_t)(q0 + w * 32 + qq * 16 + lrow) * HD + h * 32 + lkof,
                   Qst + h * 4096 + (w * 32 + qq * 16) * 32);
    #pragma unroll
    for (int h = 0; h < 2; h++)
        #pragma unroll
        for (int qq = 0; qq < 2; qq++)
            GLDS16(Kb + (size_t)(w * 32 + qq * 16 + lrow) * HD + h * 32 + lkof,
                   &KV[0][0][h * 4096 + (w * 32 + qq * 16) * 32]);
    #pragma unroll
    for (int kg = 0; kg < 4; kg++)
        GLDS16(Vtb + (size_t)(w * 16 + lrow) * SEQ + kg * 32 + lkof,
               &KV[0][1][kg * 2048 + (w * 16) * 32]);
    __syncthreads();   // all prologue staging visible

    // ---- hoist Q fragments to registers (loop-invariant) ----
    bf16x8 qf[2][2];   // [half][mi]
    #pragma unroll
    for (int h = 0; h < 2; h++)
        #pragma unroll
        for (int mi = 0; mi < 2; mi++)
            qf[h][mi] = *(const bf16x8*)&Qst[h * 4096 +
                          (w * 32 + mi * 16 + l15) * 32 + qsw];
    __syncthreads();   // Q reads done before kt=0 prefetch overwrites KV[1]

    float l_i[2] = {0.0f, 0.0f};   // per-lane partials; reduced in epilogue
    f32x4 o[2][4];
    #pragma unroll
    for (int mi = 0; mi < 2; mi++)
        #pragma unroll
        for (int db = 0; db < 4; db++) o[mi][db] = (f32x4)0.0f;

    constexpr int NT = SEQ / 128;   // 16 key tiles of 128
    for (int kt = 0; kt < NT; kt++) {
        const int cur = kt & 1, nxt = cur ^ 1;
        if (kt + 1 < NT) {
            const int k0n = (kt + 1) * 128;
            #pragma unroll
            for (int h = 0; h < 2; h++)
                #pragma unroll
                for (int qq = 0; qq < 2; qq++)
                    GLDS16(Kb + (size_t)(k0n + w * 32 + qq * 16 + lrow) * HD + h * 32 + lkof,
                           &KV[nxt][0][h * 4096 + (w * 32 + qq * 16) * 32]);
            #pragma unroll
            for (int kg = 0; kg < 4; kg++)
                GLDS16(Vtb + (size_t)(w * 16 + lrow) * SEQ + k0n + kg * 32 + lkof,
                       &KV[nxt][1][kg * 2048 + (w * 16) * 32]);
        }
        const __bf16* Ks = &KV[cur][0][0];
        const __bf16* Vs = &KV[cur][1][0];

        // two 64-key sub-phases; per-wave Pt reused with no block sync
        #pragma unroll
        for (int sub = 0; sub < 2; sub++) {
            // ---- S^T = K Q^T : 64k x 32q x 64d per wave (16 MFMAs) ----
            f32x4 st[2][4];
            #pragma unroll
            for (int mi = 0; mi < 2; mi++)
                #pragma unroll
                for (int kb = 0; kb < 4; kb++) st[mi][kb] = (f32x4)0.0f;
            __builtin_amdgcn_s_setprio(1);
            #pragma unroll
            for (int h = 0; h < 2; h++)
                #pragma unroll
                for (int kb = 0; kb < 4; kb++) {
                    const bf16x8 kf = *(const bf16x8*)&Ks[h * 4096 +
                                          (sub * 64 + kb * 16 + l15) * 32 + qsw];
                    #pragma unroll
                    for (int mi = 0; mi < 2; mi++)
                        st[mi][kb] = MFMA16(kf, qf[h][mi], st[mi][kb]);
                }
            __builtin_amdgcn_s_setprio(0);

            // ---- fixed-shift softmax: p = exp2(s), per-lane l partial ----
            #pragma unroll
            for (int mi = 0; mi < 2; mi++) {
                float rs = 0.0f;
                #pragma unroll
                for (int kb = 0; kb < 4; kb++)
                    #pragma unroll
                    for (int r = 0; r < 4; r++) {
                        const float p = EXP2(st[mi][kb][r]);
                        st[mi][kb][r] = p;
                        rs += p;
                    }
                l_i[mi] += rs;   // lane-partial; quad-reduced in epilogue
                #pragma unroll
                for (int kb = 0; kb < 4; kb++) {
                    __bf16 pb[4] = {(__bf16)st[mi][kb][0], (__bf16)st[mi][kb][1],
                                    (__bf16)st[mi][kb][2], (__bf16)st[mi][kb][3]};
                    // elem off = kb*16 + quad*4; 16B chunk = kb*2+(quad>>1)
                    const int pc = ((kb * 2 + (quad >> 1)) ^ pkey) * 8 + (quad & 1) * 4;
                    *(uint2*)&Pt[w][mi * 16 + l15][pc] = *(uint2*)pb;
                }
            }

            // ---- O^T += V^T P^T : 64d x 32q x 64k per wave (16 MFMAs) ----
            #pragma unroll
            for (int kh = 0; kh < 2; kh++) {
                bf16x8 pf[2];
                #pragma unroll
                for (int mi = 0; mi < 2; mi++) {
                    // elem off = kh*32 + quad*8; chunk = kh*4+quad
                    const int pc = ((kh * 4 + quad) ^ pkey) * 8;
                    pf[mi] = *(const bf16x8*)&Pt[w][mi * 16 + l15][pc];
                }
                __builtin_amdgcn_s_setprio(1);
                #pragma unroll
                for (int db = 0; db < 4; db++) {
                    const bf16x8 vf = *(const bf16x8*)&Vs[(sub * 2 + kh) * 2048 +
                                          (db * 16 + l15) * 32 + qsw];
                    #pragma unroll
                    for (int mi = 0; mi < 2; mi++)
                        o[mi][db] = MFMA16(vf, pf[mi], o[mi][db]);
                }
                __builtin_amdgcn_s_setprio(0);
            }
        }

        __syncthreads();   // single barrier per 128 keys
    }

    // ---- epilogue: reduce l, normalize, subtract-projection, store ----
    const float xs = xsa[0];
    const int b = bh >> 4, h = bh & (NH - 1);
    const __bf16* Vb = V + (size_t)bh * SEQ * HD;
    #pragma unroll
    for (int mi = 0; mi < 2; mi++) {
        l_i[mi] += __shfl_xor(l_i[mi], 16);
        l_i[mi] += __shfl_xor(l_i[mi], 32);
        const int q = q0 + w * 32 + mi * 16 + l15;   // sequence position
        const float inv = 1.0f / l_i[mi];
        float vv[4][4], on[4][4];
        float dp = 0.0f, nn = 0.0f;
        #pragma unroll
        for (int db = 0; db < 4; db++) {
            __bf16 vb4[4];
            *(uint2*)vb4 = *(const uint2*)&Vb[(size_t)q * HD + db * 16 + quad * 4];
            #pragma unroll
            for (int r = 0; r < 4; r++) {
                const float vf = (float)vb4[r];
                const float of = o[mi][db][r] * inv;
                vv[db][r] = vf;
                on[db][r] = of;
                dp += of * vf;
                nn += vf * vf;
            }
        }
        dp += __shfl_xor(dp, 16); dp += __shfl_xor(dp, 32);
        nn += __shfl_xor(nn, 16); nn += __shfl_xor(nn, 32);
        const float coef = xs * dp / (nn + 1e-8f);
        #pragma unroll
        for (int db = 0; db < 4; db++) {
            __bf16 ob[4];
            #pragma unroll
            for (int r = 0; r < 4; r++)
                ob[r] = (__bf16)(on[db][r] - coef * vv[db][r]);
            *(uint2*)&X2[((size_t)b * SEQ + q) * DM + h * HD + db * 16 + quad * 4] =
                *(uint2*)ob;
        }
    }
}

// ======================================================================
extern "C" void kernel_launch(void* const* d_in, const int* in_sizes, int n_in,
                              void* d_out, int out_size, void* d_ws, size_t ws_size,
                              hipStream_t stream)
{
    (void)in_sizes; (void)n_in; (void)out_size; (void)ws_size;
    const float* x   = (const float*)d_in[0];
    const float* Wq  = (const float*)d_in[1];
    const float* Wk  = (const float*)d_in[2];
    const float* Wv  = (const float*)d_in[3];
    const float* Wo  = (const float*)d_in[4];
    const float* xsa = (const float*)d_in[5];
    float* out = (float*)d_out;

    // workspace layout (bf16 elements): 56 MB total
    __bf16* xb  = (__bf16*)d_ws;        // 4 M
    __bf16* Wb  = xb  + NEL;            // 4 x 1 M (Wq,Wk,Wv,Wo)
    __bf16* Qb  = Wb  + 4 * WEL;        // 4 M  (B,H,S,HD), pre-scaled
    __bf16* Kb  = Qb  + NEL;            // 4 M
    __bf16* Vb  = Kb  + NEL;            // 4 M
    __bf16* Vtb = Vb  + NEL;            // 4 M  (B,H,HD,S)
    __bf16* X2  = Vtb + NEL;            // 4 M  (B,S,DM)

    // all fp32->bf16 conversions in one launch
    cvt_all<<<dim3(8192), 256, 0, stream>>>(x, Wq, Wk, Wv, Wo, xb, Wb);

    // Q/K/V projections (V transposed to Vt via LDS; Q pre-scaled)
    // 1D XCD-pinned grid: 8 xcd * 8 x * 12 (z,yq) = 768 blocks
    gemm_nt_mfma<128, 3><<<dim3(768), 256, 0, stream>>>(
        xb, Wb, Qb, Vtb, 1);

    // attention + fused subtract-projection -> X2 (1D XCD-pinned grid,
    // 128q / 4-wave blocks, KVBLK=128)
    attn_mfma<<<dim3((SEQ / 128) * BATCH * NH), 256, 0, stream>>>(
        Qb, Kb, Vtb, Vb, xsa, X2);

    // output projection, fp32 out; 1D XCD-pinned grid: 8*16*4 = 512 blocks
    gemm_nt_mfma<64, 1><<<dim3(512), 256, 0, stream>>>(
        X2, Wb + 3 * WEL, out, nullptr, 0);
}